// Round 5
// baseline (7199.272 us; speedup 1.0000x reference)
//
#include <hip/hip_runtime.h>
#include <hip/hip_bf16.h>
#include <math.h>

#define Hdim 512
#define Vv   100
#define V1n  101
#define Tt   20
#define Ln   2
#define Bb   1024
#define Mm   5
#define Kk   10
#define DFFn 2048

typedef unsigned short u16;
typedef __attribute__((ext_vector_type(8))) short s16x8;   // 8 bf16 = 4 VGPR MFMA frag
typedef __attribute__((ext_vector_type(16))) float f32x16; // 32x32 MFMA acc

static const size_t BH = (size_t)Bb * Hdim;

// ---- fp32 -> bf16 (RNE) and 3-way split: v ~= s0 + s1 + s2 (residual ~2^-26 rel)
__device__ __forceinline__ u16 f2bf(float f) {
    unsigned u = __float_as_uint(f);
    return (u16)((u + 0x7FFFu + ((u >> 16) & 1u)) >> 16);
}
__device__ __forceinline__ float bf2f(u16 b) { return __uint_as_float(((unsigned)b) << 16); }
__device__ __forceinline__ void split3(float v, u16* s) {
    u16 a = f2bf(v); float f0 = bf2f(a);
    float r = v - f0;
    u16 b = f2bf(r); float f1 = bf2f(b);
    s[0] = a; s[1] = b; s[2] = f2bf(r - f1);
}
// activation split write into fragment-major layout [p][h/8][1024 rows][8]
__device__ __forceinline__ void xsp_write(u16* __restrict__ xsp, int row, int h, float v)
{
    u16 s[3]; split3(v, s);
    size_t o = (size_t)(h >> 3) * 8192 + (size_t)row * 8 + (h & 7);
    xsp[o] = s[0]; xsp[BH + o] = s[1]; xsp[2 * BH + o] = s[2];
}

// ============================================================================
// Split-3 bf16 MFMA GEMM, 32x32x16 shape: C[1024][N] = A[1024][K] @ W[N][K]^T
// A: fragment-major [3][K/8][1024][8] read DIRECTLY from global (coalesced 512B).
// W: fragment-major [3][K/8][N][8]; B-tile staged in LDS (12KB/t, reg prefetch).
// Block = 128 thr = 2 waves; wave w covers rows [bm+64w, +64), cols [bn, bn+64).
// Per wave: 2x2 blocks of 32x32, acc = 4 x f32x16.  6-term split product.
// EPI: 0 = fp32 partial -> C + z*1024*N
//      1 = bias+relu -> split3 frag-major Csp (+p*cplane)
//      2 = QKV: cols[0,512)->C(q fp32), [512,1024)->kcD@pos, [1024,1536)->vcD@pos
//      3 = bias -> split3 frag-major Csp
//      4 = bias -> fp32 C row-major
// ============================================================================
template<int EPI>
__global__ __launch_bounds__(128, 2) void gemm_sp(
    const u16* __restrict__ Asp, const u16* __restrict__ Wsp,
    const float* __restrict__ bias,
    float* __restrict__ C, u16* __restrict__ Csp, size_t cplane,
    int N, int Kd, int kcount,
    float* __restrict__ kcD, float* __restrict__ vcD, int pos)
{
    __shared__ u16 sB[6144];   // [seg=p*4+kci][64 cols][8]  (12KB)
    const int tid = threadIdx.x;
    const int lane = tid & 63, w = tid >> 6;
    const int bm = blockIdx.y * 128, bn = blockIdx.x * 64;
    const int kc0 = (blockIdx.z * kcount) >> 3;
    const int nt = kcount >> 5;
    const size_t MK = (size_t)1024 * Kd;
    const size_t NK = (size_t)N * Kd;

    // B staging: 6 16B-chunks per thread; chunk cid = q*128+tid
    const u16* gB[6];
#pragma unroll
    for (int q = 0; q < 6; ++q) {
        int cid = q * 128 + tid, seg = cid >> 6, j = cid & 63;
        gB[q] = Wsp + (size_t)(seg >> 2) * NK + ((size_t)kc0 + (seg & 3)) * ((size_t)N * 8)
                    + (size_t)(bn + j) * 8;
    }
    // A per-lane base: row = bm + 64w + (lane&31), kc half = lane>>5
    const int akl = lane >> 5;
    const u16* gA = Asp + ((size_t)(kc0 + akl)) * 8192
                        + (size_t)(bm + w * 64 + (lane & 31)) * 8;

    f32x16 acc[2][2];
#pragma unroll
    for (int mi = 0; mi < 2; ++mi)
#pragma unroll
        for (int ni = 0; ni < 2; ++ni)
#pragma unroll
            for (int j = 0; j < 16; ++j) acc[mi][ni][j] = 0.f;

    s16x8 stB[6];
#pragma unroll
    for (int q = 0; q < 6; ++q) stB[q] = *(const s16x8*)(gB[q]);

    for (int t = 0; t < nt; ++t) {
        __syncthreads();
#pragma unroll
        for (int q = 0; q < 6; ++q)
            *(s16x8*)&sB[(size_t)(q * 128 + tid) * 8] = stB[q];
        __syncthreads();
        if (t + 1 < nt) {
#pragma unroll
            for (int q = 0; q < 6; ++q)
                stB[q] = *(const s16x8*)(gB[q] + (size_t)(t + 1) * 32 * N);
        }
        // A fragments for this t (direct global, coalesced)
        s16x8 a[2][2][3];   // [kk][mi][p]
#pragma unroll
        for (int kk = 0; kk < 2; ++kk)
#pragma unroll
            for (int mi = 0; mi < 2; ++mi)
#pragma unroll
                for (int p = 0; p < 3; ++p)
                    a[kk][mi][p] = *(const s16x8*)(gA + (size_t)p * MK
                                     + (size_t)(t * 4 + kk * 2) * 8192 + mi * 256);
#pragma unroll
        for (int kk = 0; kk < 2; ++kk) {
#pragma unroll
            for (int ni = 0; ni < 2; ++ni) {
                int bcol = (32 * ni + (lane & 31)) * 8;
                int srow = (2 * kk + akl) * 512;
                s16x8 b0 = *(const s16x8*)&sB[srow + bcol];
                s16x8 b1 = *(const s16x8*)&sB[2048 + srow + bcol];
                s16x8 b2 = *(const s16x8*)&sB[4096 + srow + bcol];
#pragma unroll
                for (int mi = 0; mi < 2; ++mi) {
                    f32x16 v = acc[mi][ni];
                    v = __builtin_amdgcn_mfma_f32_32x32x16_bf16(a[kk][mi][2], b0, v, 0, 0, 0);
                    v = __builtin_amdgcn_mfma_f32_32x32x16_bf16(a[kk][mi][0], b2, v, 0, 0, 0);
                    v = __builtin_amdgcn_mfma_f32_32x32x16_bf16(a[kk][mi][1], b1, v, 0, 0, 0);
                    v = __builtin_amdgcn_mfma_f32_32x32x16_bf16(a[kk][mi][1], b0, v, 0, 0, 0);
                    v = __builtin_amdgcn_mfma_f32_32x32x16_bf16(a[kk][mi][0], b1, v, 0, 0, 0);
                    v = __builtin_amdgcn_mfma_f32_32x32x16_bf16(a[kk][mi][0], b0, v, 0, 0, 0);
                    acc[mi][ni] = v;
                }
            }
        }
    }

    // epilogue: col = lane&31 (+32ni), row = (r&3)+8*(r>>2)+4*(lane>>5) (+32mi)  [m74/m101]
    const int er0 = bm + w * 64 + 4 * (lane >> 5);
    const int ec0 = bn + (lane & 31);
#pragma unroll
    for (int mi = 0; mi < 2; ++mi) {
#pragma unroll
        for (int ni = 0; ni < 2; ++ni) {
#pragma unroll
            for (int r = 0; r < 16; ++r) {
                int row = er0 + 32 * mi + (r & 3) + 8 * (r >> 2);
                int col = ec0 + 32 * ni;
                float v = acc[mi][ni][r];
                if (EPI == 0) {
                    C[(size_t)blockIdx.z * Bb * N + (size_t)row * N + col] = v;
                } else if (EPI == 1) {
                    v = fmaxf(v + bias[col], 0.f);
                    u16 s[3]; split3(v, s);
                    size_t o = (size_t)(col >> 3) * 8192 + (size_t)row * 8 + (col & 7);
                    Csp[o] = s[0]; Csp[cplane + o] = s[1]; Csp[2 * cplane + o] = s[2];
                } else if (EPI == 2) {
                    v += bias[col];
                    int seg = col >> 9, cl = col & 511;
                    float* dst = (seg == 0) ? (C + (size_t)row * Hdim)
                               : (seg == 1) ? (kcD + ((size_t)pos * Bb + row) * Hdim)
                                            : (vcD + ((size_t)pos * Bb + row) * Hdim);
                    dst[cl] = v;
                } else if (EPI == 3) {
                    v += bias[col];
                    u16 s[3]; split3(v, s);
                    size_t o = (size_t)(col >> 3) * 8192 + (size_t)row * 8 + (col & 7);
                    Csp[o] = s[0]; Csp[cplane + o] = s[1]; Csp[2 * cplane + o] = s[2];
                } else {
                    C[(size_t)row * N + col] = v + bias[col];
                }
            }
        }
    }
}

// ---------------- weight split -> fragment-major [3][K/8][N][8]
__global__ void split_mat(const float* __restrict__ src, u16* __restrict__ dst,
                          int Nn, int kbits)
{
    int i = blockIdx.x * 256 + threadIdx.x;
    int Kd = 1 << kbits;
    if (i >= Nn * Kd) return;
    int n = i >> kbits, k = i & (Kd - 1);
    u16 s[3]; split3(src[i], s);
    size_t plane = (size_t)Nn << kbits;
    size_t o = (size_t)(k >> 3) * ((size_t)Nn * 8) + (size_t)n * 8 + (k & 7);
    dst[o] = s[0]; dst[plane + o] = s[1]; dst[2 * plane + o] = s[2];
}

// ---------------- src[b,h] = sum_m emb[(meanings[b,m]+m*K), h] -> frag-major splits
__global__ void src_kernel(const int* __restrict__ meanings,
                           const float* __restrict__ emb, u16* __restrict__ ssp)
{
    int idx = blockIdx.x * 256 + threadIdx.x;
    int b = idx >> 9, h = idx & 511;
    float s = 0.f;
#pragma unroll
    for (int m = 0; m < Mm; ++m) {
        int row = meanings[b * Mm + m] + m * Kk;
        s += emb[(size_t)row * Hdim + h];
    }
    xsp_write(ssp, b, h, s);
}

// ---------------- x0 = v2e_w[:,V] + v2e_b + pe(0)
__global__ void init_x(const float* __restrict__ v2e_w, const float* __restrict__ v2e_b,
                       float* __restrict__ x, u16* __restrict__ xsp)
{
    int idx = blockIdx.x * 256 + threadIdx.x;
    int b = idx >> 9, h = idx & 511;
    float s = v2e_w[(size_t)h * V1n + Vv] + v2e_b[h] + ((h & 1) ? 1.f : 0.f);
    x[idx] = s;
    xsp_write(xsp, b, h, s);
}

// ---------------- attention vs cache (q,k,v already biased) -> frag-major split out
__global__ __launch_bounds__(256) void attn_fused(
    const float* __restrict__ qbuf, const float* __restrict__ kc,
    const float* __restrict__ vc, u16* __restrict__ osplit, int step)
{
    __shared__ float qs[Hdim];
    __shared__ float ssm[32];
    __shared__ float wts[32];
    int b = blockIdx.x, tid = threadIdx.x, lane = tid & 63, wv = tid >> 6;
    qs[tid] = qbuf[(size_t)b * Hdim + tid];
    qs[tid + 256] = qbuf[(size_t)b * Hdim + tid + 256];
    __syncthreads();
    const float4* q4 = (const float4*)qs;
    for (int t = wv; t <= step; t += 4) {
        const float4* k4 = (const float4*)(kc + ((size_t)t * Bb + b) * Hdim);
        float4 qa = q4[lane], ka = k4[lane];
        float4 qb = q4[lane + 64], kb = k4[lane + 64];
        float p = qa.x*ka.x + qa.y*ka.y + qa.z*ka.z + qa.w*ka.w
                + qb.x*kb.x + qb.y*kb.y + qb.z*kb.z + qb.w*kb.w;
#pragma unroll
        for (int off = 32; off; off >>= 1) p += __shfl_down(p, off);
        if (!lane) ssm[t] = p * 0.044194173824159216f;   // 1/sqrt(512)
    }
    __syncthreads();
    float m = -1e30f;
    for (int t = 0; t <= step; ++t) m = fmaxf(m, ssm[t]);
    float den = 0.f;
    for (int t = 0; t <= step; ++t) den += expf(ssm[t] - m);
    if (tid <= step) wts[tid] = expf(ssm[tid] - m) / den;
    __syncthreads();
#pragma unroll
    for (int c0 = 0; c0 < 2; ++c0) {
        int h = tid + c0 * 256;
        float a2 = 0.f;
        for (int t = 0; t <= step; ++t)
            a2 += wts[t] * vc[((size_t)t * Bb + b) * Hdim + h];
        xsp_write(osplit, b, h, a2);
    }
}

// ---------------- row LN stats (256 thr, 512 elems)
__device__ __forceinline__ float2 rowstats(float v0, float v1, float* sh)
{
    __syncthreads();
    float s = v0 + v1, s2 = v0 * v0 + v1 * v1;
    int lane = threadIdx.x & 63, wv = threadIdx.x >> 6;
#pragma unroll
    for (int off = 32; off; off >>= 1) {
        s += __shfl_down(s, off);
        s2 += __shfl_down(s2, off);
    }
    if (!lane) { sh[wv] = s; sh[wv + 4] = s2; }
    __syncthreads();
    float S = sh[0] + sh[1] + sh[2] + sh[3];
    float S2 = sh[4] + sh[5] + sh[6] + sh[7];
    float mean = S * (1.f / Hdim);
    float var = S2 * (1.f / Hdim) - mean * mean;
    return make_float2(mean, rsqrtf(var + 1e-5f));
}

// ---------------- x = LN2( LN1(x + Σ4 P + ob)*g0+b0 + cross )*g1+b1 ; emit splits
__global__ __launch_bounds__(256) void ln12(
    float* __restrict__ x, const float* __restrict__ P, const float* __restrict__ ob,
    const float* __restrict__ cross,
    const float* __restrict__ g0, const float* __restrict__ b0,
    const float* __restrict__ g1, const float* __restrict__ b1,
    u16* __restrict__ xsp)
{
    __shared__ float sh[8];
    size_t base = (size_t)blockIdx.x * Hdim;
    int tid = threadIdx.x;
    float v0 = x[base + tid] + ob[tid];
    float v1 = x[base + tid + 256] + ob[tid + 256];
#pragma unroll
    for (int z = 0; z < 4; ++z) {
        v0 += P[z * BH + base + tid];
        v1 += P[z * BH + base + tid + 256];
    }
    float2 st = rowstats(v0, v1, sh);
    float y0 = (v0 - st.x) * st.y * g0[tid] + b0[tid] + cross[base + tid];
    float y1 = (v1 - st.x) * st.y * g0[tid + 256] + b0[tid + 256] + cross[base + tid + 256];
    float2 s2 = rowstats(y0, y1, sh);
    float o0 = (y0 - s2.x) * s2.y * g1[tid] + b1[tid];
    float o1 = (y1 - s2.x) * s2.y * g1[tid + 256] + b1[tid + 256];
    x[base + tid] = o0; x[base + tid + 256] = o1;
    xsp_write(xsp, blockIdx.x, tid, o0);
    xsp_write(xsp, blockIdx.x, tid + 256, o1);
}

// ---------------- x = LN(x + Σ4 P + fb)*g+b ; emit splits
__global__ __launch_bounds__(256) void ln3(
    float* __restrict__ x, const float* __restrict__ P, const float* __restrict__ fb,
    const float* __restrict__ g, const float* __restrict__ bbv, u16* __restrict__ xsp)
{
    __shared__ float sh[8];
    size_t base = (size_t)blockIdx.x * Hdim;
    int tid = threadIdx.x;
    float v0 = x[base + tid] + fb[tid];
    float v1 = x[base + tid + 256] + fb[tid + 256];
#pragma unroll
    for (int z = 0; z < 4; ++z) {
        v0 += P[z * BH + base + tid];
        v1 += P[z * BH + base + tid + 256];
    }
    float2 st = rowstats(v0, v1, sh);
    float o0 = (v0 - st.x) * st.y * g[tid] + bbv[tid];
    float o1 = (v1 - st.x) * st.y * g[tid + 256] + bbv[tid + 256];
    x[base + tid] = o0; x[base + tid + 256] = o1;
    xsp_write(xsp, blockIdx.x, tid, o0);
    xsp_write(xsp, blockIdx.x, tid + 256, o1);
}

// ---------------- logits -> out ; probs = softmax ; x = probs@v2e^T + b + pe(next)
__global__ __launch_bounds__(256) void finish_step(
    const float* __restrict__ e2v_w, const float* __restrict__ e2v_b,
    const float* __restrict__ v2e_w, const float* __restrict__ v2e_b,
    float* __restrict__ out_logits, float* __restrict__ x, u16* __restrict__ xsp,
    int pos_next)
{
    __shared__ float xs[Hdim];
    __shared__ float ls[104];
    int b = blockIdx.x, tid = threadIdx.x, lane = tid & 63, wv = tid >> 6;
    xs[tid] = x[(size_t)b * Hdim + tid];
    xs[tid + 256] = x[(size_t)b * Hdim + tid + 256];
    __syncthreads();
    const float4* x4 = (const float4*)xs;
    for (int v = wv; v < V1n; v += 4) {
        const float4* w4 = (const float4*)(e2v_w + (size_t)v * Hdim);
        float4 xa = x4[lane], wa = w4[lane];
        float4 xb = x4[lane + 64], wb = w4[lane + 64];
        float p = xa.x*wa.x + xa.y*wa.y + xa.z*wa.z + xa.w*wa.w
                + xb.x*wb.x + xb.y*wb.y + xb.z*wb.z + xb.w*wb.w;
#pragma unroll
        for (int off = 32; off; off >>= 1) p += __shfl_down(p, off);
        if (!lane) ls[v] = p + e2v_b[v];
    }
    __syncthreads();
    if (tid < V1n) out_logits[(size_t)b * V1n + tid] = ls[tid];
    __syncthreads();
    if (wv == 0) {
        float a0 = (lane < V1n) ? ls[lane] : -1e30f;
        float a1 = (lane + 64 < V1n) ? ls[lane + 64] : -1e30f;
        float mm = fmaxf(a0, a1);
#pragma unroll
        for (int off = 32; off; off >>= 1) mm = fmaxf(mm, __shfl_xor(mm, off));
        float e0 = (lane < V1n) ? expf(a0 - mm) : 0.f;
        float e1 = (lane + 64 < V1n) ? expf(a1 - mm) : 0.f;
        float ssum = e0 + e1;
#pragma unroll
        for (int off = 32; off; off >>= 1) ssum += __shfl_xor(ssum, off);
        float inv = 1.f / ssum;
        if (lane < V1n) ls[lane] = e0 * inv;
        if (lane + 64 < V1n) ls[lane + 64] = e1 * inv;
    }
    __syncthreads();
    for (int h = tid; h < Hdim; h += 256) {
        const float* wr = v2e_w + (size_t)h * V1n;
        float s = v2e_b[h];
        for (int v = 0; v < V1n; ++v) s += ls[v] * wr[v];
        int j2 = h & ~1;
        float div = expf(-(float)j2 * (logf(10000.f) / (float)Hdim));
        float ang = (float)pos_next * div;
        s += (h & 1) ? cosf(ang) : sinf(ang);
        x[(size_t)b * Hdim + h] = s;
        xsp_write(xsp, b, h, s);
    }
}

extern "C" void kernel_launch(void* const* d_in, const int* in_sizes, int n_in,
                              void* d_out, int out_size, void* d_ws, size_t ws_size,
                              hipStream_t stream)
{
    const int*   meanings = (const int*)  d_in[0];
    const float* emb      = (const float*)d_in[1];
    const float* v2e_w    = (const float*)d_in[2];
    const float* v2e_b    = (const float*)d_in[3];
    const float* e2v_w    = (const float*)d_in[4];
    const float* e2v_b    = (const float*)d_in[5];
    const float* sa_in_w  = (const float*)d_in[6];
    const float* sa_in_b  = (const float*)d_in[7];
    const float* sa_out_w = (const float*)d_in[8];
    const float* sa_out_b = (const float*)d_in[9];
    const float* ca_in_w  = (const float*)d_in[10];
    const float* ca_in_b  = (const float*)d_in[11];
    const float* ca_out_w = (const float*)d_in[12];
    const float* ca_out_b = (const float*)d_in[13];
    const float* ff1_w    = (const float*)d_in[14];
    const float* ff1_b    = (const float*)d_in[15];
    const float* ff2_w    = (const float*)d_in[16];
    const float* ff2_b    = (const float*)d_in[17];
    const float* ln_g     = (const float*)d_in[18];
    const float* ln_b     = (const float*)d_in[19];
    float* out = (float*)d_out;

    // ---- ws carve-out (~238 MB)
    char* wsb = (char*)d_ws;
    auto alloc = [&](size_t bytes) {
        char* p = wsb; wsb += (bytes + 255) & ~(size_t)255; return p;
    };
    const int nsain = 1536 * 512, nsaout = 512 * 512, nff1 = 2048 * 512,
              nff2 = 512 * 2048, nca = 512 * 512;
    u16 *wsp_sa_in[2], *wsp_sa_out[2], *wsp_ff1[2], *wsp_ff2[2];
    for (int l = 0; l < 2; ++l) wsp_sa_in[l]  = (u16*)alloc((size_t)3 * nsain * 2);
    for (int l = 0; l < 2; ++l) wsp_sa_out[l] = (u16*)alloc((size_t)3 * nsaout * 2);
    for (int l = 0; l < 2; ++l) wsp_ff1[l]    = (u16*)alloc((size_t)3 * nff1 * 2);
    for (int l = 0; l < 2; ++l) wsp_ff2[l]    = (u16*)alloc((size_t)3 * nff2 * 2);
    float* x     = (float*)alloc(BH * 4);
    u16*   xsp   = (u16*)  alloc(3 * BH * 2);                // frag-major; also attn-out
    float* cross = (float*)alloc(2 * BH * 4);
    float* qbuf  = (float*)alloc(BH * 4);
    float* Pbuf  = (float*)alloc(4 * BH * 4);                // split-K partials
    u16*   h1sp  = (u16*)  alloc(3 * (size_t)Bb * DFFn * 2); // frag-major
    float* kc    = (float*)alloc((size_t)Ln * Tt * BH * 4);
    float* vc    = (float*)alloc((size_t)Ln * Tt * BH * 4);
    // setup-only aliases
    u16* ssp    = h1sp;
    u16* wspc_v = (u16*)Pbuf;
    u16* wspc_o = wspc_v + (size_t)3 * nca;
    u16* vssp   = wspc_o + (size_t)3 * nca;

    // ---- 1) split persistent weights into fragment-major bf16 planes
    const float* srcs[8] = { sa_in_w, sa_in_w + nsain, sa_out_w, sa_out_w + nsaout,
                             ff1_w, ff1_w + nff1, ff2_w, ff2_w + nff2 };
    u16* dsts[8] = { wsp_sa_in[0], wsp_sa_in[1], wsp_sa_out[0], wsp_sa_out[1],
                     wsp_ff1[0], wsp_ff1[1], wsp_ff2[0], wsp_ff2[1] };
    int nN[8] = { 1536, 1536, 512, 512, 2048, 2048, 512, 512 };
    int kb[8] = { 9, 9, 9, 9, 9, 9, 11, 11 };
    for (int i = 0; i < 8; ++i)
        split_mat<<<(nN[i] << kb[i]) / 256, 256, 0, stream>>>(srcs[i], dsts[i], nN[i], kb[i]);

    // ---- 2) setup: src embedding + per-layer cross-attn constant (S=1 shortcut)
    src_kernel<<<BH / 256, 256, 0, stream>>>(meanings, emb, ssp);
    for (int l = 0; l < Ln; ++l) {
        split_mat<<<nca / 256, 256, 0, stream>>>(
            ca_in_w + (size_t)l * 3 * Hdim * Hdim + (size_t)2 * Hdim * Hdim, wspc_v, 512, 9);
        split_mat<<<nca / 256, 256, 0, stream>>>(
            ca_out_w + (size_t)l * Hdim * Hdim, wspc_o, 512, 9);
        gemm_sp<3><<<dim3(8, 8, 1), 128, 0, stream>>>(
            ssp, wspc_v, ca_in_b + l * 1536 + 1024,
            nullptr, vssp, BH, 512, 512, 512, nullptr, nullptr, 0);
        gemm_sp<4><<<dim3(8, 8, 1), 128, 0, stream>>>(
            vssp, wspc_o, ca_out_b + l * 512,
            cross + (size_t)l * BH, nullptr, 0, 512, 512, 512, nullptr, nullptr, 0);
    }
    init_x<<<BH / 256, 256, 0, stream>>>(v2e_w, v2e_b, x, xsp);

    // ---- 3) autoregressive loop (incremental decode, KV cache)
    for (int i = 0; i < Tt; ++i) {
        for (int l = 0; l < Ln; ++l) {
            float* kcl = kc + (size_t)l * Tt * BH;
            float* vcl = vc + (size_t)l * Tt * BH;
            // QKV: N=1536, epilogue scatters q / kcache / vcache (+bias)   192 blocks
            gemm_sp<2><<<dim3(24, 8, 1), 128, 0, stream>>>(
                xsp, wsp_sa_in[l], sa_in_b + l * 1536,
                qbuf, nullptr, 0, 1536, 512, 512, kcl, vcl, i);
            attn_fused<<<Bb, 256, 0, stream>>>(qbuf, kcl, vcl, xsp, i);
            // out-proj: N=512, splitK4                                      256 blocks
            gemm_sp<0><<<dim3(8, 8, 4), 128, 0, stream>>>(
                xsp, wsp_sa_out[l], nullptr,
                Pbuf, nullptr, 0, 512, 512, 128, nullptr, nullptr, 0);
            ln12<<<Bb, 256, 0, stream>>>(x, Pbuf, sa_out_b + l * 512,
                cross + (size_t)l * BH,
                ln_g + (size_t)(l * 3 + 0) * Hdim, ln_b + (size_t)(l * 3 + 0) * Hdim,
                ln_g + (size_t)(l * 3 + 1) * Hdim, ln_b + (size_t)(l * 3 + 1) * Hdim,
                xsp);
            // FF1: N=2048, epilogue relu+bias+split3 -> h1sp frag-major     256 blocks
            gemm_sp<1><<<dim3(32, 8, 1), 128, 0, stream>>>(
                xsp, wsp_ff1[l], ff1_b + l * 2048,
                nullptr, h1sp, (size_t)Bb * DFFn, 2048, 512, 512, nullptr, nullptr, 0);
            // FF2: N=512, K=2048, splitK4                                   256 blocks
            gemm_sp<0><<<dim3(8, 8, 4), 128, 0, stream>>>(
                h1sp, wsp_ff2[l], nullptr,
                Pbuf, nullptr, 0, 512, 2048, 512, nullptr, nullptr, 0);
            ln3<<<Bb, 256, 0, stream>>>(x, Pbuf, ff2_b + l * 512,
                ln_g + (size_t)(l * 3 + 2) * Hdim, ln_b + (size_t)(l * 3 + 2) * Hdim,
                xsp);
        }
        finish_step<<<Bb, 256, 0, stream>>>(
            e2v_w, e2v_b, v2e_w, v2e_b,
            out + (size_t)i * Bb * V1n, x, xsp, i + 1);
    }
}

// Round 6
// 5130.714 us; speedup vs baseline: 1.4032x; 1.4032x over previous
//
#include <hip/hip_runtime.h>
#include <hip/hip_bf16.h>
#include <math.h>

#define Hdim 512
#define Vv   100
#define V1n  101
#define Tt   20
#define Ln   2
#define Bb   1024
#define Mm   5
#define Kk   10
#define DFFn 2048

typedef unsigned short u16;
typedef __attribute__((ext_vector_type(8))) short s16x8;   // 8 bf16 = 4 VGPR MFMA frag
typedef __attribute__((ext_vector_type(16))) float f32x16; // 32x32 MFMA acc

static const size_t BH = (size_t)Bb * Hdim;   // 524288

// ---- fp32 -> bf16 (RNE) and 3-way split: v ~= s0 + s1 + s2 (residual ~2^-26 rel)
__device__ __forceinline__ u16 f2bf(float f) {
    unsigned u = __float_as_uint(f);
    return (u16)((u + 0x7FFFu + ((u >> 16) & 1u)) >> 16);
}
__device__ __forceinline__ float bf2f(u16 b) { return __uint_as_float(((unsigned)b) << 16); }
__device__ __forceinline__ void split3(float v, u16* s) {
    u16 a = f2bf(v); float f0 = bf2f(a);
    float r = v - f0;
    u16 b = f2bf(r); float f1 = bf2f(b);
    s[0] = a; s[1] = b; s[2] = f2bf(r - f1);
}
// activation split write into fragment-major layout [p][h/8][1024 rows][8]
__device__ __forceinline__ void xsp_write(u16* __restrict__ xsp, int row, int h, float v)
{
    u16 s[3]; split3(v, s);
    size_t o = (size_t)(h >> 3) * 8192 + (size_t)row * 8 + (h & 7);
    xsp[o] = s[0]; xsp[BH + o] = s[1]; xsp[2 * BH + o] = s[2];
}

// ============================================================================
// Split-3 bf16 MFMA GEMM, 32x32x16: C[1024][N] = A[1024][K] @ W[N][K]^T
// A: frag-major [3][K/8][1024][8]; W: frag-major [3][K/8][N][8].
// Tile 128x128, 256 thr = 4 waves (2M x 2N), wave tile 64x64 (2x2 quadrants).
// BK=32 per t; A+B staged in LDS (48KB), single-buffer 2-barrier, reg prefetch.
// 6-term split product (validated R4: absmax == fp32 baseline).
// EPI: 0 = fp32 partial -> C + z*1024*N
//      3 = bias -> split3 frag-major Csp (+p*cplane)    [setup only]
//      4 = bias -> fp32 C row-major                      [setup only]
// ============================================================================
template<int EPI>
__global__ __launch_bounds__(256, 2) void gemm_sp(
    const u16* __restrict__ Asp, const u16* __restrict__ Wsp,
    const float* __restrict__ bias,
    float* __restrict__ C, u16* __restrict__ Csp, size_t cplane,
    int N, int Kd, int kcount)
{
    __shared__ u16 lds[24576];   // A: [0,12288)  B: [12288,24576)  (48KB)
    const int tid = threadIdx.x;
    const int lane = tid & 63, w = tid >> 6;
    const int wm = w >> 1, wn = w & 1;
    const int bm = blockIdx.y * 128, bn = blockIdx.x * 128;
    const int kc0 = blockIdx.z * (kcount >> 3);
    const int nt = kcount >> 5;
    const int K8 = Kd >> 3;

    // staging: 12 x 16B chunks/thread (6 A + 6 B); slab = p*4 + kc, 1024 elems
    size_t gA[6], gB[6]; int lA[6], lB[6];
#pragma unroll
    for (int q = 0; q < 6; ++q) {
        int cid = q * 256 + tid, slab = cid >> 7, win = cid & 127;
        int p = slab >> 2, kcr = slab & 3;
        gA[q] = ((size_t)p * K8 + kc0 + kcr) * 8192 + (size_t)bm * 8 + win * 8;
        lA[q] = slab * 1024 + win * 8;
        gB[q] = ((size_t)p * K8 + kc0 + kcr) * ((size_t)N * 8) + (size_t)bn * 8 + win * 8;
        lB[q] = 12288 + slab * 1024 + win * 8;
    }

    f32x16 acc[2][2];
#pragma unroll
    for (int mi = 0; mi < 2; ++mi)
#pragma unroll
        for (int ni = 0; ni < 2; ++ni)
#pragma unroll
            for (int j = 0; j < 16; ++j) acc[mi][ni][j] = 0.f;

    s16x8 rA[6], rB[6];
#pragma unroll
    for (int q = 0; q < 6; ++q) {
        rA[q] = *(const s16x8*)(Asp + gA[q]);
        rB[q] = *(const s16x8*)(Wsp + gB[q]);
    }

    for (int t = 0; t < nt; ++t) {
        __syncthreads();                       // previous tile's reads done
#pragma unroll
        for (int q = 0; q < 6; ++q) {
            *(s16x8*)&lds[lA[q]] = rA[q];
            *(s16x8*)&lds[lB[q]] = rB[q];
        }
        __syncthreads();
        if (t + 1 < nt) {                      // prefetch next t into regs
#pragma unroll
            for (int q = 0; q < 6; ++q) {
                rA[q] = *(const s16x8*)(Asp + gA[q] + (size_t)(t + 1) * 32768);
                rB[q] = *(const s16x8*)(Wsp + gB[q] + (size_t)(t + 1) * 4 * N * 8);
            }
        }
#pragma unroll
        for (int ks = 0; ks < 2; ++ks) {
            const int kb = (2 * ks + (lane >> 5)) * 1024 + (lane & 31) * 8;
            s16x8 a[2][3], b[2][3];
#pragma unroll
            for (int mi = 0; mi < 2; ++mi)
#pragma unroll
                for (int p = 0; p < 3; ++p)
                    a[mi][p] = *(const s16x8*)&lds[p * 4096 + kb + (64 * wm + 32 * mi) * 8];
#pragma unroll
            for (int ni = 0; ni < 2; ++ni)
#pragma unroll
                for (int p = 0; p < 3; ++p)
                    b[ni][p] = *(const s16x8*)&lds[12288 + p * 4096 + kb + (64 * wn + 32 * ni) * 8];
#pragma unroll
            for (int mi = 0; mi < 2; ++mi)
#pragma unroll
                for (int ni = 0; ni < 2; ++ni) {
                    f32x16 v = acc[mi][ni];
                    v = __builtin_amdgcn_mfma_f32_32x32x16_bf16(a[mi][2], b[ni][0], v, 0, 0, 0);
                    v = __builtin_amdgcn_mfma_f32_32x32x16_bf16(a[mi][0], b[ni][2], v, 0, 0, 0);
                    v = __builtin_amdgcn_mfma_f32_32x32x16_bf16(a[mi][1], b[ni][1], v, 0, 0, 0);
                    v = __builtin_amdgcn_mfma_f32_32x32x16_bf16(a[mi][1], b[ni][0], v, 0, 0, 0);
                    v = __builtin_amdgcn_mfma_f32_32x32x16_bf16(a[mi][0], b[ni][1], v, 0, 0, 0);
                    v = __builtin_amdgcn_mfma_f32_32x32x16_bf16(a[mi][0], b[ni][0], v, 0, 0, 0);
                    acc[mi][ni] = v;
                }
        }
    }

    // epilogue: col = lane&31 (+32ni+64wn), row = (r&3)+8*(r>>2)+4*(lane>>5) (+32mi+64wm)
    const int er0 = bm + 64 * wm + 4 * (lane >> 5);
    const int ec0 = bn + 64 * wn + (lane & 31);
#pragma unroll
    for (int mi = 0; mi < 2; ++mi) {
#pragma unroll
        for (int ni = 0; ni < 2; ++ni) {
            int col = ec0 + 32 * ni;
#pragma unroll
            for (int r = 0; r < 16; ++r) {
                int row = er0 + 32 * mi + (r & 3) + 8 * (r >> 2);
                float v = acc[mi][ni][r];
                if (EPI == 0) {
                    C[(size_t)blockIdx.z * Bb * N + (size_t)row * N + col] = v;
                } else if (EPI == 3) {
                    v += bias[col];
                    u16 s[3]; split3(v, s);
                    size_t o = (size_t)(col >> 3) * 8192 + (size_t)row * 8 + (col & 7);
                    Csp[o] = s[0]; Csp[cplane + o] = s[1]; Csp[2 * cplane + o] = s[2];
                } else {
                    C[(size_t)row * N + col] = v + bias[col];
                }
            }
        }
    }
}

// ---------------- weight split -> fragment-major [3][K/8][N][8]
__global__ void split_mat(const float* __restrict__ src, u16* __restrict__ dst,
                          int Nn, int kbits)
{
    int i = blockIdx.x * 256 + threadIdx.x;
    int Kd = 1 << kbits;
    if (i >= Nn * Kd) return;
    int n = i >> kbits, k = i & (Kd - 1);
    u16 s[3]; split3(src[i], s);
    size_t plane = (size_t)Nn << kbits;
    size_t o = (size_t)(k >> 3) * ((size_t)Nn * 8) + (size_t)n * 8 + (k & 7);
    dst[o] = s[0]; dst[plane + o] = s[1]; dst[2 * plane + o] = s[2];
}

// ---------------- src[b,h] = sum_m emb[(meanings[b,m]+m*K), h] -> frag-major splits
__global__ void src_kernel(const int* __restrict__ meanings,
                           const float* __restrict__ emb, u16* __restrict__ ssp)
{
    int idx = blockIdx.x * 256 + threadIdx.x;
    int b = idx >> 9, h = idx & 511;
    float s = 0.f;
#pragma unroll
    for (int m = 0; m < Mm; ++m) {
        int row = meanings[b * Mm + m] + m * Kk;
        s += emb[(size_t)row * Hdim + h];
    }
    xsp_write(ssp, b, h, s);
}

// ---------------- x0 = v2e_w[:,V] + v2e_b + pe(0)
__global__ void init_x(const float* __restrict__ v2e_w, const float* __restrict__ v2e_b,
                       float* __restrict__ x, u16* __restrict__ xsp)
{
    int idx = blockIdx.x * 256 + threadIdx.x;
    int b = idx >> 9, h = idx & 511;
    float s = v2e_w[(size_t)h * V1n + Vv] + v2e_b[h] + ((h & 1) ? 1.f : 0.f);
    x[idx] = s;
    xsp_write(xsp, b, h, s);
}

// ---------------- QKV combine (2 split-K partials + bias) + KV store + attention
__global__ __launch_bounds__(256) void attn_fused(
    const float* __restrict__ P, const float* __restrict__ bias3h,
    float* __restrict__ kc, float* __restrict__ vc,
    u16* __restrict__ osplit, int step)
{
    __shared__ float qs[Hdim];
    __shared__ float ssm[32];
    __shared__ float wts[32];
    int b = blockIdx.x, tid = threadIdx.x, lane = tid & 63, wv = tid >> 6;
    const size_t PS = (size_t)Bb * 1536;
    const float* pb = P + (size_t)b * 1536;
#pragma unroll
    for (int c0 = 0; c0 < 2; ++c0) {
        int c = tid + c0 * 256;
        float qv = bias3h[c]        + pb[c]        + pb[PS + c];
        float kv = bias3h[512 + c]  + pb[512 + c]  + pb[PS + 512 + c];
        float vv = bias3h[1024 + c] + pb[1024 + c] + pb[PS + 1024 + c];
        qs[c] = qv;
        kc[((size_t)step * Bb + b) * Hdim + c] = kv;
        vc[((size_t)step * Bb + b) * Hdim + c] = vv;
    }
    __syncthreads();
    const float4* q4 = (const float4*)qs;
    for (int t = wv; t <= step; t += 4) {
        const float4* k4 = (const float4*)(kc + ((size_t)t * Bb + b) * Hdim);
        float4 qa = q4[lane], ka = k4[lane];
        float4 qb = q4[lane + 64], kb = k4[lane + 64];
        float p = qa.x*ka.x + qa.y*ka.y + qa.z*ka.z + qa.w*ka.w
                + qb.x*kb.x + qb.y*kb.y + qb.z*kb.z + qb.w*kb.w;
#pragma unroll
        for (int off = 32; off; off >>= 1) p += __shfl_down(p, off);
        if (!lane) ssm[t] = p * 0.044194173824159216f;   // 1/sqrt(512)
    }
    __syncthreads();
    float m = -1e30f;
    for (int t = 0; t <= step; ++t) m = fmaxf(m, ssm[t]);
    float den = 0.f;
    for (int t = 0; t <= step; ++t) den += expf(ssm[t] - m);
    if (tid <= step) wts[tid] = expf(ssm[tid] - m) / den;
    __syncthreads();
#pragma unroll
    for (int c0 = 0; c0 < 2; ++c0) {
        int h = tid + c0 * 256;
        float a2 = 0.f;
        for (int t = 0; t <= step; ++t)
            a2 += wts[t] * vc[((size_t)t * Bb + b) * Hdim + h];
        xsp_write(osplit, b, h, a2);
    }
}

// ---------------- row LN stats (256 thr, 512 elems)
__device__ __forceinline__ float2 rowstats(float v0, float v1, float* sh)
{
    __syncthreads();
    float s = v0 + v1, s2 = v0 * v0 + v1 * v1;
    int lane = threadIdx.x & 63, wv = threadIdx.x >> 6;
#pragma unroll
    for (int off = 32; off; off >>= 1) {
        s += __shfl_down(s, off);
        s2 += __shfl_down(s2, off);
    }
    if (!lane) { sh[wv] = s; sh[wv + 4] = s2; }
    __syncthreads();
    float S = sh[0] + sh[1] + sh[2] + sh[3];
    float S2 = sh[4] + sh[5] + sh[6] + sh[7];
    float mean = S * (1.f / Hdim);
    float var = S2 * (1.f / Hdim) - mean * mean;
    return make_float2(mean, rsqrtf(var + 1e-5f));
}

// ---------------- x = LN2( LN1(x + Σ8 P + ob)*g0+b0 + cross )*g1+b1 ; emit splits
__global__ __launch_bounds__(256) void ln12(
    float* __restrict__ x, const float* __restrict__ P, const float* __restrict__ ob,
    const float* __restrict__ cross,
    const float* __restrict__ g0, const float* __restrict__ b0,
    const float* __restrict__ g1, const float* __restrict__ b1,
    u16* __restrict__ xsp)
{
    __shared__ float sh[8];
    size_t base = (size_t)blockIdx.x * Hdim;
    int tid = threadIdx.x;
    float v0 = x[base + tid] + ob[tid];
    float v1 = x[base + tid + 256] + ob[tid + 256];
#pragma unroll
    for (int z = 0; z < 8; ++z) {
        v0 += P[z * BH + base + tid];
        v1 += P[z * BH + base + tid + 256];
    }
    float2 st = rowstats(v0, v1, sh);
    float y0 = (v0 - st.x) * st.y * g0[tid] + b0[tid] + cross[base + tid];
    float y1 = (v1 - st.x) * st.y * g0[tid + 256] + b0[tid + 256] + cross[base + tid + 256];
    float2 s2 = rowstats(y0, y1, sh);
    float o0 = (y0 - s2.x) * s2.y * g1[tid] + b1[tid];
    float o1 = (y1 - s2.x) * s2.y * g1[tid + 256] + b1[tid + 256];
    x[base + tid] = o0; x[base + tid + 256] = o1;
    xsp_write(xsp, blockIdx.x, tid, o0);
    xsp_write(xsp, blockIdx.x, tid + 256, o1);
}

// ---------------- x = LN(x + Σ8 P + fb)*g+b ; emit splits
__global__ __launch_bounds__(256) void ln3(
    float* __restrict__ x, const float* __restrict__ P, const float* __restrict__ fb,
    const float* __restrict__ g, const float* __restrict__ bbv, u16* __restrict__ xsp)
{
    __shared__ float sh[8];
    size_t base = (size_t)blockIdx.x * Hdim;
    int tid = threadIdx.x;
    float v0 = x[base + tid] + fb[tid];
    float v1 = x[base + tid + 256] + fb[tid + 256];
#pragma unroll
    for (int z = 0; z < 8; ++z) {
        v0 += P[z * BH + base + tid];
        v1 += P[z * BH + base + tid + 256];
    }
    float2 st = rowstats(v0, v1, sh);
    float o0 = (v0 - st.x) * st.y * g[tid] + bbv[tid];
    float o1 = (v1 - st.x) * st.y * g[tid + 256] + bbv[tid + 256];
    x[base + tid] = o0; x[base + tid + 256] = o1;
    xsp_write(xsp, blockIdx.x, tid, o0);
    xsp_write(xsp, blockIdx.x, tid + 256, o1);
}

// ---------------- FF1 combine: h1 = relu(Σ2 P + bias) -> frag-major split planes
__global__ void ff1_combine(const float* __restrict__ P, const float* __restrict__ bias,
                            u16* __restrict__ hsp)
{
    const size_t PS = (size_t)Bb * DFFn;
    size_t base = ((size_t)blockIdx.x * 256 + threadIdx.x) * 4;
    int row = (int)(base >> 11), col = (int)(base & (DFFn - 1));
    float4 s = *(const float4*)(bias + col);
    float4 p0 = *(const float4*)(P + base);
    float4 p1 = *(const float4*)(P + PS + base);
    float vv[4] = { fmaxf(s.x + p0.x + p1.x, 0.f), fmaxf(s.y + p0.y + p1.y, 0.f),
                    fmaxf(s.z + p0.z + p1.z, 0.f), fmaxf(s.w + p0.w + p1.w, 0.f) };
    size_t o = (size_t)(col >> 3) * 8192 + (size_t)row * 8 + (col & 7);
#pragma unroll
    for (int j = 0; j < 4; ++j) {
        u16 t3[3]; split3(vv[j], t3);
        hsp[o + j] = t3[0]; hsp[PS + o + j] = t3[1]; hsp[2 * PS + o + j] = t3[2];
    }
}

// ---------------- logits -> out ; probs = softmax ; x = probs@v2e^T + b + pe(next)
__global__ __launch_bounds__(256) void finish_step(
    const float* __restrict__ e2v_w, const float* __restrict__ e2v_b,
    const float* __restrict__ v2e_w, const float* __restrict__ v2e_b,
    float* __restrict__ out_logits, float* __restrict__ x, u16* __restrict__ xsp,
    int pos_next)
{
    __shared__ float xs[Hdim];
    __shared__ float ls[104];
    int b = blockIdx.x, tid = threadIdx.x, lane = tid & 63, wv = tid >> 6;
    xs[tid] = x[(size_t)b * Hdim + tid];
    xs[tid + 256] = x[(size_t)b * Hdim + tid + 256];
    __syncthreads();
    const float4* x4 = (const float4*)xs;
    for (int v = wv; v < V1n; v += 4) {
        const float4* w4 = (const float4*)(e2v_w + (size_t)v * Hdim);
        float4 xa = x4[lane], wa = w4[lane];
        float4 xb = x4[lane + 64], wb = w4[lane + 64];
        float p = xa.x*wa.x + xa.y*wa.y + xa.z*wa.z + xa.w*wa.w
                + xb.x*wb.x + xb.y*wb.y + xb.z*wb.z + xb.w*wb.w;
#pragma unroll
        for (int off = 32; off; off >>= 1) p += __shfl_down(p, off);
        if (!lane) ls[v] = p + e2v_b[v];
    }
    __syncthreads();
    if (tid < V1n) out_logits[(size_t)b * V1n + tid] = ls[tid];
    __syncthreads();
    if (wv == 0) {
        float a0 = (lane < V1n) ? ls[lane] : -1e30f;
        float a1 = (lane + 64 < V1n) ? ls[lane + 64] : -1e30f;
        float mm = fmaxf(a0, a1);
#pragma unroll
        for (int off = 32; off; off >>= 1) mm = fmaxf(mm, __shfl_xor(mm, off));
        float e0 = (lane < V1n) ? expf(a0 - mm) : 0.f;
        float e1 = (lane + 64 < V1n) ? expf(a1 - mm) : 0.f;
        float ssum = e0 + e1;
#pragma unroll
        for (int off = 32; off; off >>= 1) ssum += __shfl_xor(ssum, off);
        float inv = 1.f / ssum;
        if (lane < V1n) ls[lane] = e0 * inv;
        if (lane + 64 < V1n) ls[lane + 64] = e1 * inv;
    }
    __syncthreads();
    for (int h = tid; h < Hdim; h += 256) {
        const float* wr = v2e_w + (size_t)h * V1n;
        float s = v2e_b[h];
        for (int v = 0; v < V1n; ++v) s += ls[v] * wr[v];
        int j2 = h & ~1;
        float div = expf(-(float)j2 * (logf(10000.f) / (float)Hdim));
        float ang = (float)pos_next * div;
        s += (h & 1) ? cosf(ang) : sinf(ang);
        x[(size_t)b * Hdim + h] = s;
        xsp_write(xsp, b, h, s);
    }
}

extern "C" void kernel_launch(void* const* d_in, const int* in_sizes, int n_in,
                              void* d_out, int out_size, void* d_ws, size_t ws_size,
                              hipStream_t stream)
{
    const int*   meanings = (const int*)  d_in[0];
    const float* emb      = (const float*)d_in[1];
    const float* v2e_w    = (const float*)d_in[2];
    const float* v2e_b    = (const float*)d_in[3];
    const float* e2v_w    = (const float*)d_in[4];
    const float* e2v_b    = (const float*)d_in[5];
    const float* sa_in_w  = (const float*)d_in[6];
    const float* sa_in_b  = (const float*)d_in[7];
    const float* sa_out_w = (const float*)d_in[8];
    const float* sa_out_b = (const float*)d_in[9];
    const float* ca_in_w  = (const float*)d_in[10];
    const float* ca_in_b  = (const float*)d_in[11];
    const float* ca_out_w = (const float*)d_in[12];
    const float* ca_out_b = (const float*)d_in[13];
    const float* ff1_w    = (const float*)d_in[14];
    const float* ff1_b    = (const float*)d_in[15];
    const float* ff2_w    = (const float*)d_in[16];
    const float* ff2_b    = (const float*)d_in[17];
    const float* ln_g     = (const float*)d_in[18];
    const float* ln_b     = (const float*)d_in[19];
    float* out = (float*)d_out;

    // ---- ws carve-out (~245 MB)
    char* wsb = (char*)d_ws;
    auto alloc = [&](size_t bytes) {
        char* p = wsb; wsb += (bytes + 255) & ~(size_t)255; return p;
    };
    const int nsain = 1536 * 512, nsaout = 512 * 512, nff1 = 2048 * 512,
              nff2 = 512 * 2048, nca = 512 * 512;
    u16 *wsp_sa_in[2], *wsp_sa_out[2], *wsp_ff1[2], *wsp_ff2[2];
    for (int l = 0; l < 2; ++l) wsp_sa_in[l]  = (u16*)alloc((size_t)3 * nsain * 2);
    for (int l = 0; l < 2; ++l) wsp_sa_out[l] = (u16*)alloc((size_t)3 * nsaout * 2);
    for (int l = 0; l < 2; ++l) wsp_ff1[l]    = (u16*)alloc((size_t)3 * nff1 * 2);
    for (int l = 0; l < 2; ++l) wsp_ff2[l]    = (u16*)alloc((size_t)3 * nff2 * 2);
    float* x     = (float*)alloc(BH * 4);
    u16*   xsp   = (u16*)  alloc(3 * BH * 2);                // frag-major; also attn-out
    float* cross = (float*)alloc(2 * BH * 4);
    float* Pbuf  = (float*)alloc(8 * BH * 4);                // split-K partials (16.8MB)
    u16*   h1sp  = (u16*)  alloc(3 * (size_t)Bb * DFFn * 2); // frag-major
    float* kc    = (float*)alloc((size_t)Ln * Tt * BH * 4);
    float* vc    = (float*)alloc((size_t)Ln * Tt * BH * 4);
    // setup-only aliases
    u16* ssp    = h1sp;
    u16* wspc_v = (u16*)Pbuf;
    u16* wspc_o = wspc_v + (size_t)3 * nca;
    u16* vssp   = wspc_o + (size_t)3 * nca;

    // ---- 1) split persistent weights into fragment-major bf16 planes
    const float* srcs[8] = { sa_in_w, sa_in_w + nsain, sa_out_w, sa_out_w + nsaout,
                             ff1_w, ff1_w + nff1, ff2_w, ff2_w + nff2 };
    u16* dsts[8] = { wsp_sa_in[0], wsp_sa_in[1], wsp_sa_out[0], wsp_sa_out[1],
                     wsp_ff1[0], wsp_ff1[1], wsp_ff2[0], wsp_ff2[1] };
    int nN[8] = { 1536, 1536, 512, 512, 2048, 2048, 512, 512 };
    int kb[8] = { 9, 9, 9, 9, 9, 9, 11, 11 };
    for (int i = 0; i < 8; ++i)
        split_mat<<<(nN[i] << kb[i]) / 256, 256, 0, stream>>>(srcs[i], dsts[i], nN[i], kb[i]);

    // ---- 2) setup: src embedding + per-layer cross-attn constant (S=1 shortcut)
    src_kernel<<<BH / 256, 256, 0, stream>>>(meanings, emb, ssp);
    for (int l = 0; l < Ln; ++l) {
        split_mat<<<nca / 256, 256, 0, stream>>>(
            ca_in_w + (size_t)l * 3 * Hdim * Hdim + (size_t)2 * Hdim * Hdim, wspc_v, 512, 9);
        split_mat<<<nca / 256, 256, 0, stream>>>(
            ca_out_w + (size_t)l * Hdim * Hdim, wspc_o, 512, 9);
        gemm_sp<3><<<dim3(4, 8, 1), 256, 0, stream>>>(
            ssp, wspc_v, ca_in_b + l * 1536 + 1024,
            nullptr, vssp, BH, 512, 512, 512);
        gemm_sp<4><<<dim3(4, 8, 1), 256, 0, stream>>>(
            vssp, wspc_o, ca_out_b + l * 512,
            cross + (size_t)l * BH, nullptr, 0, 512, 512, 512);
    }
    init_x<<<BH / 256, 256, 0, stream>>>(v2e_w, v2e_b, x, xsp);

    // ---- 3) autoregressive loop (incremental decode, KV cache)
    for (int i = 0; i < Tt; ++i) {
        for (int l = 0; l < Ln; ++l) {
            float* kcl = kc + (size_t)l * Tt * BH;
            float* vcl = vc + (size_t)l * Tt * BH;
            // QKV: N=1536, splitK2 -> 192 blocks; combined in attn_fused
            gemm_sp<0><<<dim3(12, 8, 2), 256, 0, stream>>>(
                xsp, wsp_sa_in[l], nullptr,
                Pbuf, nullptr, 0, 1536, 512, 256);
            attn_fused<<<Bb, 256, 0, stream>>>(Pbuf, sa_in_b + l * 1536,
                                               kcl, vcl, xsp, i);
            // out-proj: N=512, splitK8 -> 256 blocks
            gemm_sp<0><<<dim3(4, 8, 8), 256, 0, stream>>>(
                xsp, wsp_sa_out[l], nullptr,
                Pbuf, nullptr, 0, 512, 512, 64);
            ln12<<<Bb, 256, 0, stream>>>(x, Pbuf, sa_out_b + l * 512,
                cross + (size_t)l * BH,
                ln_g + (size_t)(l * 3 + 0) * Hdim, ln_b + (size_t)(l * 3 + 0) * Hdim,
                ln_g + (size_t)(l * 3 + 1) * Hdim, ln_b + (size_t)(l * 3 + 1) * Hdim,
                xsp);
            // FF1: N=2048, splitK2 -> 256 blocks
            gemm_sp<0><<<dim3(16, 8, 2), 256, 0, stream>>>(
                xsp, wsp_ff1[l], nullptr,
                Pbuf, nullptr, 0, 2048, 512, 256);
            ff1_combine<<<(Bb * DFFn / 4) / 256, 256, 0, stream>>>(
                Pbuf, ff1_b + l * 2048, h1sp);
            // FF2: N=512, K=2048, splitK8 -> 256 blocks
            gemm_sp<0><<<dim3(4, 8, 8), 256, 0, stream>>>(
                h1sp, wsp_ff2[l], nullptr,
                Pbuf, nullptr, 0, 512, 2048, 256);
            ln3<<<Bb, 256, 0, stream>>>(x, Pbuf, ff2_b + l * 512,
                ln_g + (size_t)(l * 3 + 2) * Hdim, ln_b + (size_t)(l * 3 + 2) * Hdim,
                xsp);
        }
        finish_step<<<Bb, 256, 0, stream>>>(
            e2v_w, e2v_b, v2e_w, v2e_b,
            out + (size_t)i * Bb * V1n, x, xsp, i + 1);
    }
}

// Round 7
// 4812.843 us; speedup vs baseline: 1.4958x; 1.0660x over previous
//
#include <hip/hip_runtime.h>
#include <hip/hip_bf16.h>
#include <math.h>

#define Hdim 512
#define Vv   100
#define V1n  101
#define Tt   20
#define Ln   2
#define Bb   1024
#define Mm   5
#define Kk   10
#define DFFn 2048

typedef unsigned short u16;
typedef __attribute__((ext_vector_type(8))) short s16x8;   // 8 bf16 = 4 VGPR MFMA frag
typedef __attribute__((ext_vector_type(16))) float f32x16; // 32x32 MFMA acc

static const size_t BH  = (size_t)Bb * Hdim;   // 524288
static const size_t PSP = (size_t)Bb * 128;    // probs plane elems (K padded 101->128)

// ---- fp32 -> bf16 (RNE) and 3-way split: v ~= s0 + s1 + s2 (residual ~2^-26 rel)
__device__ __forceinline__ u16 f2bf(float f) {
    unsigned u = __float_as_uint(f);
    return (u16)((u + 0x7FFFu + ((u >> 16) & 1u)) >> 16);
}
__device__ __forceinline__ float bf2f(u16 b) { return __uint_as_float(((unsigned)b) << 16); }
__device__ __forceinline__ void split3(float v, u16* s) {
    u16 a = f2bf(v); float f0 = bf2f(a);
    float r = v - f0;
    u16 b = f2bf(r); float f1 = bf2f(b);
    s[0] = a; s[1] = b; s[2] = f2bf(r - f1);
}
// activation split write into fragment-major layout [p][h/8][1024 rows][8]
__device__ __forceinline__ void xsp_write(u16* __restrict__ xsp, int row, int h, float v)
{
    u16 s[3]; split3(v, s);
    size_t o = (size_t)(h >> 3) * 8192 + (size_t)row * 8 + (h & 7);
    xsp[o] = s[0]; xsp[BH + o] = s[1]; xsp[2 * BH + o] = s[2];
}

// ============================================================================
// Split-3 bf16 MFMA GEMM, 32x32x16: C[1024][N] = A[1024][K] @ W[N][K]^T
// A: frag-major [3][K/8][1024][8]; W: frag-major [3][K/8][N][8].
// Tile 128x128, 256 thr = 4 waves (2M x 2N), wave tile 64x64 (2x2 quadrants).
// BK=32/t; A+B staged in LDS (48KB), single-buffer 2-barrier, reg prefetch.
// 6-term split product (validated R3-R5: absmax == fp32 baseline).
// EPI: 0 = fp32 partial -> C + z*1024*N
//      1 = bias+relu -> split3 frag-major Csp (+p*cplane)
//      3 = bias -> split3 frag-major Csp                  [setup only]
//      4 = bias -> fp32 C row-major                       [setup only]
//      5 = bias + pos-encoding(posn) -> fp32 x (N=512) AND split3 Csp
// ============================================================================
template<int EPI>
__global__ __launch_bounds__(256, 2) void gemm_sp(
    const u16* __restrict__ Asp, const u16* __restrict__ Wsp,
    const float* __restrict__ bias,
    float* __restrict__ C, u16* __restrict__ Csp, size_t cplane,
    int N, int Kd, int kcount, int posn)
{
    __shared__ u16 lds[24576];   // A: [0,12288)  B: [12288,24576)  (48KB)
    const int tid = threadIdx.x;
    const int lane = tid & 63, w = tid >> 6;
    const int wm = w >> 1, wn = w & 1;
    const int bm = blockIdx.y * 128, bn = blockIdx.x * 128;
    const int kc0 = blockIdx.z * (kcount >> 3);
    const int nt = kcount >> 5;
    const int K8 = Kd >> 3;

    // staging: 12 x 16B chunks/thread (6 A + 6 B); slab = p*4 + kc, 1024 elems
    size_t gA[6], gB[6]; int lA[6], lB[6];
#pragma unroll
    for (int q = 0; q < 6; ++q) {
        int cid = q * 256 + tid, slab = cid >> 7, win = cid & 127;
        int p = slab >> 2, kcr = slab & 3;
        gA[q] = ((size_t)p * K8 + kc0 + kcr) * 8192 + (size_t)bm * 8 + win * 8;
        lA[q] = slab * 1024 + win * 8;
        gB[q] = ((size_t)p * K8 + kc0 + kcr) * ((size_t)N * 8) + (size_t)bn * 8 + win * 8;
        lB[q] = 12288 + slab * 1024 + win * 8;
    }

    f32x16 acc[2][2];
#pragma unroll
    for (int mi = 0; mi < 2; ++mi)
#pragma unroll
        for (int ni = 0; ni < 2; ++ni)
#pragma unroll
            for (int j = 0; j < 16; ++j) acc[mi][ni][j] = 0.f;

    s16x8 rA[6], rB[6];
#pragma unroll
    for (int q = 0; q < 6; ++q) {
        rA[q] = *(const s16x8*)(Asp + gA[q]);
        rB[q] = *(const s16x8*)(Wsp + gB[q]);
    }

    for (int t = 0; t < nt; ++t) {
        __syncthreads();                       // previous tile's reads done
#pragma unroll
        for (int q = 0; q < 6; ++q) {
            *(s16x8*)&lds[lA[q]] = rA[q];
            *(s16x8*)&lds[lB[q]] = rB[q];
        }
        __syncthreads();
        if (t + 1 < nt) {                      // prefetch next t into regs
#pragma unroll
            for (int q = 0; q < 6; ++q) {
                rA[q] = *(const s16x8*)(Asp + gA[q] + (size_t)(t + 1) * 32768);
                rB[q] = *(const s16x8*)(Wsp + gB[q] + (size_t)(t + 1) * 32 * N);
            }
        }
#pragma unroll
        for (int ks = 0; ks < 2; ++ks) {
            const int kb = (2 * ks + (lane >> 5)) * 1024 + (lane & 31) * 8;
            s16x8 a[2][3], b[2][3];
#pragma unroll
            for (int mi = 0; mi < 2; ++mi)
#pragma unroll
                for (int p = 0; p < 3; ++p)
                    a[mi][p] = *(const s16x8*)&lds[p * 4096 + kb + (64 * wm + 32 * mi) * 8];
#pragma unroll
            for (int ni = 0; ni < 2; ++ni)
#pragma unroll
                for (int p = 0; p < 3; ++p)
                    b[ni][p] = *(const s16x8*)&lds[12288 + p * 4096 + kb + (64 * wn + 32 * ni) * 8];
#pragma unroll
            for (int mi = 0; mi < 2; ++mi)
#pragma unroll
                for (int ni = 0; ni < 2; ++ni) {
                    f32x16 v = acc[mi][ni];
                    v = __builtin_amdgcn_mfma_f32_32x32x16_bf16(a[mi][2], b[ni][0], v, 0, 0, 0);
                    v = __builtin_amdgcn_mfma_f32_32x32x16_bf16(a[mi][0], b[ni][2], v, 0, 0, 0);
                    v = __builtin_amdgcn_mfma_f32_32x32x16_bf16(a[mi][1], b[ni][1], v, 0, 0, 0);
                    v = __builtin_amdgcn_mfma_f32_32x32x16_bf16(a[mi][1], b[ni][0], v, 0, 0, 0);
                    v = __builtin_amdgcn_mfma_f32_32x32x16_bf16(a[mi][0], b[ni][1], v, 0, 0, 0);
                    v = __builtin_amdgcn_mfma_f32_32x32x16_bf16(a[mi][0], b[ni][0], v, 0, 0, 0);
                    acc[mi][ni] = v;
                }
        }
    }

    // epilogue: col = lane&31 (+32ni+64wn), row = (r&3)+8*(r>>2)+4*(lane>>5) (+32mi+64wm)
    const int er0 = bm + 64 * wm + 4 * (lane >> 5);
    const int ec0 = bn + 64 * wn + (lane & 31);
#pragma unroll
    for (int mi = 0; mi < 2; ++mi) {
#pragma unroll
        for (int ni = 0; ni < 2; ++ni) {
            int col = ec0 + 32 * ni;
#pragma unroll
            for (int r = 0; r < 16; ++r) {
                int row = er0 + 32 * mi + (r & 3) + 8 * (r >> 2);
                float v = acc[mi][ni][r];
                if (EPI == 0) {
                    C[(size_t)blockIdx.z * Bb * N + (size_t)row * N + col] = v;
                } else if (EPI == 1) {
                    v = fmaxf(v + bias[col], 0.f);
                    u16 s[3]; split3(v, s);
                    size_t o = (size_t)(col >> 3) * 8192 + (size_t)row * 8 + (col & 7);
                    Csp[o] = s[0]; Csp[cplane + o] = s[1]; Csp[2 * cplane + o] = s[2];
                } else if (EPI == 3) {
                    v += bias[col];
                    u16 s[3]; split3(v, s);
                    size_t o = (size_t)(col >> 3) * 8192 + (size_t)row * 8 + (col & 7);
                    Csp[o] = s[0]; Csp[cplane + o] = s[1]; Csp[2 * cplane + o] = s[2];
                } else if (EPI == 4) {
                    C[(size_t)row * N + col] = v + bias[col];
                } else if (EPI == 5) {
                    v += bias[col];
                    int j2 = col & ~1;
                    float div = expf(-(float)j2 * (logf(10000.f) / (float)Hdim));
                    float ang = (float)posn * div;
                    v += (col & 1) ? cosf(ang) : sinf(ang);
                    C[(size_t)row * Hdim + col] = v;
                    u16 s[3]; split3(v, s);
                    size_t o = (size_t)(col >> 3) * 8192 + (size_t)row * 8 + (col & 7);
                    Csp[o] = s[0]; Csp[cplane + o] = s[1]; Csp[2 * cplane + o] = s[2];
                }
            }
        }
    }
}

// ---------------- weight split -> fragment-major [3][Kpad/8][Npad][8], zero-padded
__global__ void split_mat(const float* __restrict__ src, u16* __restrict__ dst,
                          int Nreal, int Npad, int Kreal, int kpl)
{
    int i = blockIdx.x * 256 + threadIdx.x;
    int Kpad = 1 << kpl;
    if (i >= (Npad << kpl)) return;
    int n = i >> kpl, k = i & (Kpad - 1);
    float v = (n < Nreal && k < Kreal) ? src[(size_t)n * Kreal + k] : 0.f;
    u16 s[3]; split3(v, s);
    size_t plane = (size_t)Npad << kpl;
    size_t o = (size_t)(k >> 3) * ((size_t)Npad * 8) + (size_t)n * 8 + (k & 7);
    dst[o] = s[0]; dst[plane + o] = s[1]; dst[2 * plane + o] = s[2];
}

// ---------------- src[b,h] = sum_m emb[(meanings[b,m]+m*K), h] -> frag-major splits
__global__ void src_kernel(const int* __restrict__ meanings,
                           const float* __restrict__ emb, u16* __restrict__ ssp)
{
    int idx = blockIdx.x * 256 + threadIdx.x;
    int b = idx >> 9, h = idx & 511;
    float s = 0.f;
#pragma unroll
    for (int m = 0; m < Mm; ++m) {
        int row = meanings[b * Mm + m] + m * Kk;
        s += emb[(size_t)row * Hdim + h];
    }
    xsp_write(ssp, b, h, s);
}

// ---------------- x0 = v2e_w[:,V] + v2e_b + pe(0)
__global__ void init_x(const float* __restrict__ v2e_w, const float* __restrict__ v2e_b,
                       float* __restrict__ x, u16* __restrict__ xsp)
{
    int idx = blockIdx.x * 256 + threadIdx.x;
    int b = idx >> 9, h = idx & 511;
    float s = v2e_w[(size_t)h * V1n + Vv] + v2e_b[h] + ((h & 1) ? 1.f : 0.f);
    x[idx] = s;
    xsp_write(xsp, b, h, s);
}

// ---------------- QKV combine (2 split-K partials + bias) + KV store + attention
__global__ __launch_bounds__(256) void attn_fused(
    const float* __restrict__ P, const float* __restrict__ bias3h,
    float* __restrict__ kc, float* __restrict__ vc,
    u16* __restrict__ osplit, int step)
{
    __shared__ float qs[Hdim];
    __shared__ float ssm[32];
    __shared__ float wts[32];
    int b = blockIdx.x, tid = threadIdx.x, lane = tid & 63, wv = tid >> 6;
    const size_t PS = (size_t)Bb * 1536;
    const float* pb = P + (size_t)b * 1536;
#pragma unroll
    for (int c0 = 0; c0 < 2; ++c0) {
        int c = tid + c0 * 256;
        float qv = bias3h[c]        + pb[c]        + pb[PS + c];
        float kv = bias3h[512 + c]  + pb[512 + c]  + pb[PS + 512 + c];
        float vv = bias3h[1024 + c] + pb[1024 + c] + pb[PS + 1024 + c];
        qs[c] = qv;
        kc[((size_t)step * Bb + b) * Hdim + c] = kv;
        vc[((size_t)step * Bb + b) * Hdim + c] = vv;
    }
    __syncthreads();
    const float4* q4 = (const float4*)qs;
    for (int t = wv; t <= step; t += 4) {
        const float4* k4 = (const float4*)(kc + ((size_t)t * Bb + b) * Hdim);
        float4 qa = q4[lane], ka = k4[lane];
        float4 qb = q4[lane + 64], kb = k4[lane + 64];
        float p = qa.x*ka.x + qa.y*ka.y + qa.z*ka.z + qa.w*ka.w
                + qb.x*kb.x + qb.y*kb.y + qb.z*kb.z + qb.w*kb.w;
#pragma unroll
        for (int off = 32; off; off >>= 1) p += __shfl_down(p, off);
        if (!lane) ssm[t] = p * 0.044194173824159216f;   // 1/sqrt(512)
    }
    __syncthreads();
    float m = -1e30f;
    for (int t = 0; t <= step; ++t) m = fmaxf(m, ssm[t]);
    float den = 0.f;
    for (int t = 0; t <= step; ++t) den += expf(ssm[t] - m);
    if (tid <= step) wts[tid] = expf(ssm[tid] - m) / den;
    __syncthreads();
#pragma unroll
    for (int c0 = 0; c0 < 2; ++c0) {
        int h = tid + c0 * 256;
        float a2 = 0.f;
        for (int t = 0; t <= step; ++t)
            a2 += wts[t] * vc[((size_t)t * Bb + b) * Hdim + h];
        xsp_write(osplit, b, h, a2);
    }
}

// ---------------- row LN stats (256 thr, 512 elems)
__device__ __forceinline__ float2 rowstats(float v0, float v1, float* sh)
{
    __syncthreads();
    float s = v0 + v1, s2 = v0 * v0 + v1 * v1;
    int lane = threadIdx.x & 63, wv = threadIdx.x >> 6;
#pragma unroll
    for (int off = 32; off; off >>= 1) {
        s += __shfl_down(s, off);
        s2 += __shfl_down(s2, off);
    }
    if (!lane) { sh[wv] = s; sh[wv + 4] = s2; }
    __syncthreads();
    float S = sh[0] + sh[1] + sh[2] + sh[3];
    float S2 = sh[4] + sh[5] + sh[6] + sh[7];
    float mean = S * (1.f / Hdim);
    float var = S2 * (1.f / Hdim) - mean * mean;
    return make_float2(mean, rsqrtf(var + 1e-5f));
}

// ---------------- x = LN2( LN1(x + ΣNZ P + ob)*g0+b0 + cross )*g1+b1 ; emit splits
template<int NZ>
__global__ __launch_bounds__(256) void ln12(
    float* __restrict__ x, const float* __restrict__ P, const float* __restrict__ ob,
    const float* __restrict__ cross,
    const float* __restrict__ g0, const float* __restrict__ b0,
    const float* __restrict__ g1, const float* __restrict__ b1,
    u16* __restrict__ xsp)
{
    __shared__ float sh[8];
    size_t base = (size_t)blockIdx.x * Hdim;
    int tid = threadIdx.x;
    float v0 = x[base + tid] + ob[tid];
    float v1 = x[base + tid + 256] + ob[tid + 256];
#pragma unroll
    for (int z = 0; z < NZ; ++z) {
        v0 += P[z * BH + base + tid];
        v1 += P[z * BH + base + tid + 256];
    }
    float2 st = rowstats(v0, v1, sh);
    float y0 = (v0 - st.x) * st.y * g0[tid] + b0[tid] + cross[base + tid];
    float y1 = (v1 - st.x) * st.y * g0[tid + 256] + b0[tid + 256] + cross[base + tid + 256];
    float2 s2 = rowstats(y0, y1, sh);
    float o0 = (y0 - s2.x) * s2.y * g1[tid] + b1[tid];
    float o1 = (y1 - s2.x) * s2.y * g1[tid + 256] + b1[tid + 256];
    x[base + tid] = o0; x[base + tid + 256] = o1;
    xsp_write(xsp, blockIdx.x, tid, o0);
    xsp_write(xsp, blockIdx.x, tid + 256, o1);
}

// ---------------- x = LN(x + ΣNZ P + fb)*g+b ; emit splits
template<int NZ>
__global__ __launch_bounds__(256) void ln3(
    float* __restrict__ x, const float* __restrict__ P, const float* __restrict__ fb,
    const float* __restrict__ g, const float* __restrict__ bbv, u16* __restrict__ xsp)
{
    __shared__ float sh[8];
    size_t base = (size_t)blockIdx.x * Hdim;
    int tid = threadIdx.x;
    float v0 = x[base + tid] + fb[tid];
    float v1 = x[base + tid + 256] + fb[tid + 256];
#pragma unroll
    for (int z = 0; z < NZ; ++z) {
        v0 += P[z * BH + base + tid];
        v1 += P[z * BH + base + tid + 256];
    }
    float2 st = rowstats(v0, v1, sh);
    float o0 = (v0 - st.x) * st.y * g[tid] + bbv[tid];
    float o1 = (v1 - st.x) * st.y * g[tid + 256] + bbv[tid + 256];
    x[base + tid] = o0; x[base + tid + 256] = o1;
    xsp_write(xsp, blockIdx.x, tid, o0);
    xsp_write(xsp, blockIdx.x, tid + 256, o1);
}

// ---------------- combine 4 logit partials + bias -> out; softmax -> psp splits
__global__ __launch_bounds__(128) void softmax_out(
    const float* __restrict__ P, const float* __restrict__ e2v_b,
    float* __restrict__ out_i, u16* __restrict__ psp)
{
    __shared__ float red[4];
    int b = blockIdx.x, v = threadIdx.x, lane = v & 63, wv = v >> 6;
    bool valid = v < V1n;
    float s = -1e30f;
    if (valid) {
        s = e2v_b[v];
#pragma unroll
        for (int z = 0; z < 4; ++z) s += P[(size_t)z * Bb * 128 + (size_t)b * 128 + v];
        out_i[(size_t)b * V1n + v] = s;
    }
    float m = s;
#pragma unroll
    for (int off = 32; off; off >>= 1) m = fmaxf(m, __shfl_xor(m, off));
    if (!lane) red[wv] = m;
    __syncthreads();
    float M = fmaxf(red[0], red[1]);
    float e = valid ? expf(s - M) : 0.f;
    float d = e;
#pragma unroll
    for (int off = 32; off; off >>= 1) d += __shfl_xor(d, off);
    if (!lane) red[2 + wv] = d;
    __syncthreads();
    float D = red[2] + red[3];
    float p = valid ? e / D : 0.f;     // zero for pad cols 101..127
    u16 t3[3]; split3(p, t3);
    size_t o = (size_t)(v >> 3) * 8192 + (size_t)b * 8 + (v & 7);
    psp[o] = t3[0]; psp[PSP + o] = t3[1]; psp[2 * PSP + o] = t3[2];
}

extern "C" void kernel_launch(void* const* d_in, const int* in_sizes, int n_in,
                              void* d_out, int out_size, void* d_ws, size_t ws_size,
                              hipStream_t stream)
{
    const int*   meanings = (const int*)  d_in[0];
    const float* emb      = (const float*)d_in[1];
    const float* v2e_w    = (const float*)d_in[2];
    const float* v2e_b    = (const float*)d_in[3];
    const float* e2v_w    = (const float*)d_in[4];
    const float* e2v_b    = (const float*)d_in[5];
    const float* sa_in_w  = (const float*)d_in[6];
    const float* sa_in_b  = (const float*)d_in[7];
    const float* sa_out_w = (const float*)d_in[8];
    const float* sa_out_b = (const float*)d_in[9];
    const float* ca_in_w  = (const float*)d_in[10];
    const float* ca_in_b  = (const float*)d_in[11];
    const float* ca_out_w = (const float*)d_in[12];
    const float* ca_out_b = (const float*)d_in[13];
    const float* ff1_w    = (const float*)d_in[14];
    const float* ff1_b    = (const float*)d_in[15];
    const float* ff2_w    = (const float*)d_in[16];
    const float* ff2_b    = (const float*)d_in[17];
    const float* ln_g     = (const float*)d_in[18];
    const float* ln_b     = (const float*)d_in[19];
    float* out = (float*)d_out;

    // ---- ws carve-out (~248 MB)
    char* wsb = (char*)d_ws;
    auto alloc = [&](size_t bytes) {
        char* p = wsb; wsb += (bytes + 255) & ~(size_t)255; return p;
    };
    const int nsain = 1536 * 512, nsaout = 512 * 512, nff1 = 2048 * 512,
              nff2 = 512 * 2048, nca = 512 * 512;
    u16 *wsp_sa_in[2], *wsp_sa_out[2], *wsp_ff1[2], *wsp_ff2[2];
    for (int l = 0; l < 2; ++l) wsp_sa_in[l]  = (u16*)alloc((size_t)3 * nsain * 2);
    for (int l = 0; l < 2; ++l) wsp_sa_out[l] = (u16*)alloc((size_t)3 * nsaout * 2);
    for (int l = 0; l < 2; ++l) wsp_ff1[l]    = (u16*)alloc((size_t)3 * nff1 * 2);
    for (int l = 0; l < 2; ++l) wsp_ff2[l]    = (u16*)alloc((size_t)3 * nff2 * 2);
    float* x       = (float*)alloc(BH * 4);
    u16*   xsp     = (u16*)  alloc(3 * BH * 2);                // frag-major; also attn-out
    float* cross   = (float*)alloc(2 * BH * 4);
    float* Pbuf    = (float*)alloc(8 * BH * 4);                // split-K partials (16.8MB)
    u16*   h1sp    = (u16*)  alloc(3 * (size_t)Bb * DFFn * 2); // frag-major
    u16*   psp     = (u16*)  alloc(3 * PSP * 2);               // probs splits (K pad 128)
    u16*   e2v_wsp = (u16*)  alloc((size_t)3 * 128 * 512 * 2); // N pad 101->128
    u16*   v2e_wsp = (u16*)  alloc((size_t)3 * 512 * 128 * 2); // K pad 101->128
    float* kc      = (float*)alloc((size_t)Ln * Tt * BH * 4);
    float* vc      = (float*)alloc((size_t)Ln * Tt * BH * 4);
    // setup-only aliases
    u16* ssp    = h1sp;
    u16* wspc_v = (u16*)Pbuf;
    u16* wspc_o = wspc_v + (size_t)3 * nca;
    u16* vssp   = wspc_o + (size_t)3 * nca;

    // ---- 1) split persistent weights into fragment-major bf16 planes
    const float* srcs[8] = { sa_in_w, sa_in_w + nsain, sa_out_w, sa_out_w + nsaout,
                             ff1_w, ff1_w + nff1, ff2_w, ff2_w + nff2 };
    u16* dsts[8] = { wsp_sa_in[0], wsp_sa_in[1], wsp_sa_out[0], wsp_sa_out[1],
                     wsp_ff1[0], wsp_ff1[1], wsp_ff2[0], wsp_ff2[1] };
    int nN[8] = { 1536, 1536, 512, 512, 2048, 2048, 512, 512 };
    int kb[8] = { 9, 9, 9, 9, 9, 9, 11, 11 };
    for (int i = 0; i < 8; ++i)
        split_mat<<<(nN[i] << kb[i]) / 256, 256, 0, stream>>>(
            srcs[i], dsts[i], nN[i], nN[i], 1 << kb[i], kb[i]);
    // vocab projections (padded)
    split_mat<<<(128 << 9) / 256, 256, 0, stream>>>(e2v_w, e2v_wsp, V1n, 128, 512, 9);
    split_mat<<<(512 << 7) / 256, 256, 0, stream>>>(v2e_w, v2e_wsp, 512, 512, V1n, 7);

    // ---- 2) setup: src embedding + per-layer cross-attn constant (S=1 shortcut)
    src_kernel<<<BH / 256, 256, 0, stream>>>(meanings, emb, ssp);
    for (int l = 0; l < Ln; ++l) {
        split_mat<<<nca / 256, 256, 0, stream>>>(
            ca_in_w + (size_t)l * 3 * Hdim * Hdim + (size_t)2 * Hdim * Hdim,
            wspc_v, 512, 512, 512, 9);
        split_mat<<<nca / 256, 256, 0, stream>>>(
            ca_out_w + (size_t)l * Hdim * Hdim, wspc_o, 512, 512, 512, 9);
        gemm_sp<3><<<dim3(4, 8, 1), 256, 0, stream>>>(
            ssp, wspc_v, ca_in_b + l * 1536 + 1024,
            nullptr, vssp, BH, 512, 512, 512, 0);
        gemm_sp<4><<<dim3(4, 8, 1), 256, 0, stream>>>(
            vssp, wspc_o, ca_out_b + l * 512,
            cross + (size_t)l * BH, nullptr, 0, 512, 512, 512, 0);
    }
    init_x<<<BH / 256, 256, 0, stream>>>(v2e_w, v2e_b, x, xsp);

    // ---- 3) autoregressive loop (incremental decode, KV cache)
    for (int i = 0; i < Tt; ++i) {
        for (int l = 0; l < Ln; ++l) {
            float* kcl = kc + (size_t)l * Tt * BH;
            float* vcl = vc + (size_t)l * Tt * BH;
            // QKV: N=1536, splitK2 -> 192 blocks; combined in attn_fused
            gemm_sp<0><<<dim3(12, 8, 2), 256, 0, stream>>>(
                xsp, wsp_sa_in[l], nullptr,
                Pbuf, nullptr, 0, 1536, 512, 256, 0);
            attn_fused<<<Bb, 256, 0, stream>>>(Pbuf, sa_in_b + l * 1536,
                                               kcl, vcl, xsp, i);
            // out-proj: N=512, splitK8 -> 256 blocks
            gemm_sp<0><<<dim3(4, 8, 8), 256, 0, stream>>>(
                xsp, wsp_sa_out[l], nullptr,
                Pbuf, nullptr, 0, 512, 512, 64, 0);
            ln12<8><<<Bb, 256, 0, stream>>>(x, Pbuf, sa_out_b + l * 512,
                cross + (size_t)l * BH,
                ln_g + (size_t)(l * 3 + 0) * Hdim, ln_b + (size_t)(l * 3 + 0) * Hdim,
                ln_g + (size_t)(l * 3 + 1) * Hdim, ln_b + (size_t)(l * 3 + 1) * Hdim,
                xsp);
            // FF1: N=2048, no split-K, epilogue relu+bias+split3 -> h1sp (128 blocks)
            gemm_sp<1><<<dim3(16, 8, 1), 256, 0, stream>>>(
                xsp, wsp_ff1[l], ff1_b + l * 2048,
                nullptr, h1sp, (size_t)Bb * DFFn, 2048, 512, 512, 0);
            // FF2: N=512, K=2048, splitK8 -> 256 blocks
            gemm_sp<0><<<dim3(4, 8, 8), 256, 0, stream>>>(
                h1sp, wsp_ff2[l], nullptr,
                Pbuf, nullptr, 0, 512, 2048, 256, 0);
            ln3<8><<<Bb, 256, 0, stream>>>(x, Pbuf, ff2_b + l * 512,
                ln_g + (size_t)(l * 3 + 2) * Hdim, ln_b + (size_t)(l * 3 + 2) * Hdim,
                xsp);
        }
        // logits: N=128 (pad of 101), splitK4 -> 32 blocks, partials in Pbuf
        gemm_sp<0><<<dim3(1, 8, 4), 256, 0, stream>>>(
            xsp, e2v_wsp, nullptr, Pbuf, nullptr, 0, 128, 512, 128, 0);
        // combine + write out[i] + softmax -> psp splits
        softmax_out<<<Bb, 128, 0, stream>>>(
            Pbuf, e2v_b, out + (size_t)i * Bb * V1n, psp);
        // x-update: x = probs @ v2e^T + b + pe(i+1)  (K=128 pad of 101)
        if (i + 1 < Tt)
            gemm_sp<5><<<dim3(4, 8, 1), 256, 0, stream>>>(
                psp, v2e_wsp, v2e_b, x, xsp, BH, 512, 128, 128, i + 1);
    }
}

// Round 8
// 3727.428 us; speedup vs baseline: 1.9314x; 1.2912x over previous
//
#include <hip/hip_runtime.h>
#include <hip/hip_bf16.h>
#include <math.h>

#define Hdim 512
#define Vv   100
#define V1n  101
#define Tt   20
#define Ln   2
#define Bb   1024
#define Mm   5
#define Kk   10
#define DFFn 2048

typedef _Float16 f16;
typedef __attribute__((ext_vector_type(8))) _Float16 f16x8; // 8 f16 = 4 VGPR MFMA frag
typedef __attribute__((ext_vector_type(16))) float f32x16;  // 32x32 MFMA acc

static const size_t BH  = (size_t)Bb * Hdim;   // 524288
static const size_t PSP = (size_t)Bb * 128;    // probs plane elems (K padded 101->128)

// ---- fp32 -> fp16 split-2: v = h0 + h1 + O(2^-22 v)   (Markidis/Ootomo basis)
__device__ __forceinline__ void split2(float v, f16* s) {
    f16 h0 = (f16)v;
    float r = v - (float)h0;
    s[0] = h0; s[1] = (f16)r;
}
// activation split write into fragment-major layout [p][h/8][1024 rows][8]
__device__ __forceinline__ void xsp_write(f16* __restrict__ xsp, int row, int h, float v)
{
    f16 s[2]; split2(v, s);
    size_t o = (size_t)(h >> 3) * 8192 + (size_t)row * 8 + (h & 7);
    xsp[o] = s[0]; xsp[BH + o] = s[1];
}

// ============================================================================
// Split-2 fp16 MFMA GEMM, 32x32x16: C[1024][N] = A[1024][K] @ W[N][K]^T
// A: frag-major [2][K/8][1024][8]; W: frag-major [2][K/8][N][8].
// Tile 128x128, 256 thr = 4 waves (2M x 2N), wave tile 64x64 (2x2 quadrants).
// BK=32/t; A+B staged in LDS (32KB), single-buffer 2-barrier, reg prefetch.
// 3-term product a0b0+a1b0+a0b1 -> ~2^-22 relative (fp32-grade).
// EPI: 0 = fp32 partial -> C + z*1024*N
//      1 = bias+relu -> split2 frag-major Csp (+p*cplane)
//      3 = bias -> split2 frag-major Csp                  [setup only]
//      4 = bias -> fp32 C row-major                       [setup only]
//      5 = bias + pos-encoding(posn) -> fp32 x (N=512) AND split2 Csp
// ============================================================================
template<int EPI>
__global__ __launch_bounds__(256, 2) void gemm_sp(
    const f16* __restrict__ Asp, const f16* __restrict__ Wsp,
    const float* __restrict__ bias,
    float* __restrict__ C, f16* __restrict__ Csp, size_t cplane,
    int N, int Kd, int kcount, int posn)
{
    __shared__ f16 lds[16384];   // A: [0,8192)  B: [8192,16384)  (32KB)
    const int tid = threadIdx.x;
    const int lane = tid & 63, w = tid >> 6;
    const int wm = w >> 1, wn = w & 1;
    const int bm = blockIdx.y * 128, bn = blockIdx.x * 128;
    const int kc0 = blockIdx.z * (kcount >> 3);
    const int nt = kcount >> 5;
    const int K8 = Kd >> 3;

    // staging: 8 x 16B chunks/thread (4 A + 4 B); slab = p*4 + kcr, 1024 elems
    size_t gA[4], gB[4]; int lA[4], lB[4];
#pragma unroll
    for (int q = 0; q < 4; ++q) {
        int cid = q * 256 + tid, slab = cid >> 7, win = cid & 127;
        int p = slab >> 2, kcr = slab & 3;
        gA[q] = ((size_t)p * K8 + kc0 + kcr) * 8192 + (size_t)bm * 8 + win * 8;
        lA[q] = slab * 1024 + win * 8;
        gB[q] = ((size_t)p * K8 + kc0 + kcr) * ((size_t)N * 8) + (size_t)bn * 8 + win * 8;
        lB[q] = 8192 + slab * 1024 + win * 8;
    }

    f32x16 acc[2][2];
#pragma unroll
    for (int mi = 0; mi < 2; ++mi)
#pragma unroll
        for (int ni = 0; ni < 2; ++ni)
#pragma unroll
            for (int j = 0; j < 16; ++j) acc[mi][ni][j] = 0.f;

    f16x8 rA[4], rB[4];
#pragma unroll
    for (int q = 0; q < 4; ++q) {
        rA[q] = *(const f16x8*)(Asp + gA[q]);
        rB[q] = *(const f16x8*)(Wsp + gB[q]);
    }

    for (int t = 0; t < nt; ++t) {
        __syncthreads();                       // previous tile's reads done
#pragma unroll
        for (int q = 0; q < 4; ++q) {
            *(f16x8*)&lds[lA[q]] = rA[q];
            *(f16x8*)&lds[lB[q]] = rB[q];
        }
        __syncthreads();
        if (t + 1 < nt) {                      // prefetch next t into regs
#pragma unroll
            for (int q = 0; q < 4; ++q) {
                rA[q] = *(const f16x8*)(Asp + gA[q] + (size_t)(t + 1) * 32768);
                rB[q] = *(const f16x8*)(Wsp + gB[q] + (size_t)(t + 1) * 32 * N);
            }
        }
#pragma unroll
        for (int ks = 0; ks < 2; ++ks) {
            const int kb = (2 * ks + (lane >> 5)) * 1024 + (lane & 31) * 8;
            f16x8 a[2][2], b[2][2];   // [mi|ni][plane]
#pragma unroll
            for (int mi = 0; mi < 2; ++mi)
#pragma unroll
                for (int p = 0; p < 2; ++p)
                    a[mi][p] = *(const f16x8*)&lds[p * 4096 + kb + (64 * wm + 32 * mi) * 8];
#pragma unroll
            for (int ni = 0; ni < 2; ++ni)
#pragma unroll
                for (int p = 0; p < 2; ++p)
                    b[ni][p] = *(const f16x8*)&lds[8192 + p * 4096 + kb + (64 * wn + 32 * ni) * 8];
#pragma unroll
            for (int mi = 0; mi < 2; ++mi)
#pragma unroll
                for (int ni = 0; ni < 2; ++ni) {
                    f32x16 v = acc[mi][ni];
                    v = __builtin_amdgcn_mfma_f32_32x32x16_f16(a[mi][1], b[ni][0], v, 0, 0, 0);
                    v = __builtin_amdgcn_mfma_f32_32x32x16_f16(a[mi][0], b[ni][1], v, 0, 0, 0);
                    v = __builtin_amdgcn_mfma_f32_32x32x16_f16(a[mi][0], b[ni][0], v, 0, 0, 0);
                    acc[mi][ni] = v;
                }
        }
    }

    // epilogue: col = lane&31 (+32ni+64wn), row = (r&3)+8*(r>>2)+4*(lane>>5) (+32mi+64wm)
    const int er0 = bm + 64 * wm + 4 * (lane >> 5);
    const int ec0 = bn + 64 * wn + (lane & 31);
#pragma unroll
    for (int mi = 0; mi < 2; ++mi) {
#pragma unroll
        for (int ni = 0; ni < 2; ++ni) {
            int col = ec0 + 32 * ni;
#pragma unroll
            for (int r = 0; r < 16; ++r) {
                int row = er0 + 32 * mi + (r & 3) + 8 * (r >> 2);
                float v = acc[mi][ni][r];
                if (EPI == 0) {
                    C[(size_t)blockIdx.z * Bb * N + (size_t)row * N + col] = v;
                } else if (EPI == 1) {
                    v = fmaxf(v + bias[col], 0.f);
                    f16 s[2]; split2(v, s);
                    size_t o = (size_t)(col >> 3) * 8192 + (size_t)row * 8 + (col & 7);
                    Csp[o] = s[0]; Csp[cplane + o] = s[1];
                } else if (EPI == 3) {
                    v += bias[col];
                    f16 s[2]; split2(v, s);
                    size_t o = (size_t)(col >> 3) * 8192 + (size_t)row * 8 + (col & 7);
                    Csp[o] = s[0]; Csp[cplane + o] = s[1];
                } else if (EPI == 4) {
                    C[(size_t)row * N + col] = v + bias[col];
                } else if (EPI == 5) {
                    v += bias[col];
                    int j2 = col & ~1;
                    float div = expf(-(float)j2 * (logf(10000.f) / (float)Hdim));
                    float ang = (float)posn * div;
                    v += (col & 1) ? cosf(ang) : sinf(ang);
                    C[(size_t)row * Hdim + col] = v;
                    f16 s[2]; split2(v, s);
                    size_t o = (size_t)(col >> 3) * 8192 + (size_t)row * 8 + (col & 7);
                    Csp[o] = s[0]; Csp[cplane + o] = s[1];
                }
            }
        }
    }
}

// ---------------- weight split -> fragment-major [2][Kpad/8][Npad][8], zero-padded
__global__ void split_mat(const float* __restrict__ src, f16* __restrict__ dst,
                          int Nreal, int Npad, int Kreal, int kpl)
{
    int i = blockIdx.x * 256 + threadIdx.x;
    int Kpad = 1 << kpl;
    if (i >= (Npad << kpl)) return;
    int n = i >> kpl, k = i & (Kpad - 1);
    float v = (n < Nreal && k < Kreal) ? src[(size_t)n * Kreal + k] : 0.f;
    f16 s[2]; split2(v, s);
    size_t plane = (size_t)Npad << kpl;
    size_t o = (size_t)(k >> 3) * ((size_t)Npad * 8) + (size_t)n * 8 + (k & 7);
    dst[o] = s[0]; dst[plane + o] = s[1];
}

// ---------------- src[b,h] = sum_m emb[(meanings[b,m]+m*K), h] -> frag-major splits
__global__ void src_kernel(const int* __restrict__ meanings,
                           const float* __restrict__ emb, f16* __restrict__ ssp)
{
    int idx = blockIdx.x * 256 + threadIdx.x;
    int b = idx >> 9, h = idx & 511;
    float s = 0.f;
#pragma unroll
    for (int m = 0; m < Mm; ++m) {
        int row = meanings[b * Mm + m] + m * Kk;
        s += emb[(size_t)row * Hdim + h];
    }
    xsp_write(ssp, b, h, s);
}

// ---------------- x0 = v2e_w[:,V] + v2e_b + pe(0)
__global__ void init_x(const float* __restrict__ v2e_w, const float* __restrict__ v2e_b,
                       float* __restrict__ x, f16* __restrict__ xsp)
{
    int idx = blockIdx.x * 256 + threadIdx.x;
    int b = idx >> 9, h = idx & 511;
    float s = v2e_w[(size_t)h * V1n + Vv] + v2e_b[h] + ((h & 1) ? 1.f : 0.f);
    x[idx] = s;
    xsp_write(xsp, b, h, s);
}

// ---------------- QKV combine (2 split-K partials + bias) + KV store + attention
__global__ __launch_bounds__(256) void attn_fused(
    const float* __restrict__ P, const float* __restrict__ bias3h,
    float* __restrict__ kc, float* __restrict__ vc,
    f16* __restrict__ osplit, int step)
{
    __shared__ float qs[Hdim];
    __shared__ float ssm[32];
    __shared__ float wts[32];
    int b = blockIdx.x, tid = threadIdx.x, lane = tid & 63, wv = tid >> 6;
    const size_t PS = (size_t)Bb * 1536;
    const float* pb = P + (size_t)b * 1536;
#pragma unroll
    for (int c0 = 0; c0 < 2; ++c0) {
        int c = tid + c0 * 256;
        float qv = bias3h[c]        + pb[c]        + pb[PS + c];
        float kv = bias3h[512 + c]  + pb[512 + c]  + pb[PS + 512 + c];
        float vv = bias3h[1024 + c] + pb[1024 + c] + pb[PS + 1024 + c];
        qs[c] = qv;
        kc[((size_t)step * Bb + b) * Hdim + c] = kv;
        vc[((size_t)step * Bb + b) * Hdim + c] = vv;
    }
    __syncthreads();
    const float4* q4 = (const float4*)qs;
    for (int t = wv; t <= step; t += 4) {
        const float4* k4 = (const float4*)(kc + ((size_t)t * Bb + b) * Hdim);
        float4 qa = q4[lane], ka = k4[lane];
        float4 qb = q4[lane + 64], kb = k4[lane + 64];
        float p = qa.x*ka.x + qa.y*ka.y + qa.z*ka.z + qa.w*ka.w
                + qb.x*kb.x + qb.y*kb.y + qb.z*kb.z + qb.w*kb.w;
#pragma unroll
        for (int off = 32; off; off >>= 1) p += __shfl_down(p, off);
        if (!lane) ssm[t] = p * 0.044194173824159216f;   // 1/sqrt(512)
    }
    __syncthreads();
    float m = -1e30f;
    for (int t = 0; t <= step; ++t) m = fmaxf(m, ssm[t]);
    float den = 0.f;
    for (int t = 0; t <= step; ++t) den += expf(ssm[t] - m);
    if (tid <= step) wts[tid] = expf(ssm[tid] - m) / den;
    __syncthreads();
#pragma unroll
    for (int c0 = 0; c0 < 2; ++c0) {
        int h = tid + c0 * 256;
        float a2 = 0.f;
        for (int t = 0; t <= step; ++t)
            a2 += wts[t] * vc[((size_t)t * Bb + b) * Hdim + h];
        xsp_write(osplit, b, h, a2);
    }
}

// ---------------- row LN stats (256 thr, 512 elems)
__device__ __forceinline__ float2 rowstats(float v0, float v1, float* sh)
{
    __syncthreads();
    float s = v0 + v1, s2 = v0 * v0 + v1 * v1;
    int lane = threadIdx.x & 63, wv = threadIdx.x >> 6;
#pragma unroll
    for (int off = 32; off; off >>= 1) {
        s += __shfl_down(s, off);
        s2 += __shfl_down(s2, off);
    }
    if (!lane) { sh[wv] = s; sh[wv + 4] = s2; }
    __syncthreads();
    float S = sh[0] + sh[1] + sh[2] + sh[3];
    float S2 = sh[4] + sh[5] + sh[6] + sh[7];
    float mean = S * (1.f / Hdim);
    float var = S2 * (1.f / Hdim) - mean * mean;
    return make_float2(mean, rsqrtf(var + 1e-5f));
}

// ---------------- x = LN2( LN1(x + ΣNZ P + ob)*g0+b0 + cross )*g1+b1 ; emit splits
template<int NZ>
__global__ __launch_bounds__(256) void ln12(
    float* __restrict__ x, const float* __restrict__ P, const float* __restrict__ ob,
    const float* __restrict__ cross,
    const float* __restrict__ g0, const float* __restrict__ b0,
    const float* __restrict__ g1, const float* __restrict__ b1,
    f16* __restrict__ xsp)
{
    __shared__ float sh[8];
    size_t base = (size_t)blockIdx.x * Hdim;
    int tid = threadIdx.x;
    float v0 = x[base + tid] + ob[tid];
    float v1 = x[base + tid + 256] + ob[tid + 256];
#pragma unroll
    for (int z = 0; z < NZ; ++z) {
        v0 += P[z * BH + base + tid];
        v1 += P[z * BH + base + tid + 256];
    }
    float2 st = rowstats(v0, v1, sh);
    float y0 = (v0 - st.x) * st.y * g0[tid] + b0[tid] + cross[base + tid];
    float y1 = (v1 - st.x) * st.y * g0[tid + 256] + b0[tid + 256] + cross[base + tid + 256];
    float2 s2 = rowstats(y0, y1, sh);
    float o0 = (y0 - s2.x) * s2.y * g1[tid] + b1[tid];
    float o1 = (y1 - s2.x) * s2.y * g1[tid + 256] + b1[tid + 256];
    x[base + tid] = o0; x[base + tid + 256] = o1;
    xsp_write(xsp, blockIdx.x, tid, o0);
    xsp_write(xsp, blockIdx.x, tid + 256, o1);
}

// ---------------- x = LN(x + ΣNZ P + fb)*g+b ; emit splits
template<int NZ>
__global__ __launch_bounds__(256) void ln3(
    float* __restrict__ x, const float* __restrict__ P, const float* __restrict__ fb,
    const float* __restrict__ g, const float* __restrict__ bbv, f16* __restrict__ xsp)
{
    __shared__ float sh[8];
    size_t base = (size_t)blockIdx.x * Hdim;
    int tid = threadIdx.x;
    float v0 = x[base + tid] + fb[tid];
    float v1 = x[base + tid + 256] + fb[tid + 256];
#pragma unroll
    for (int z = 0; z < NZ; ++z) {
        v0 += P[z * BH + base + tid];
        v1 += P[z * BH + base + tid + 256];
    }
    float2 st = rowstats(v0, v1, sh);
    float o0 = (v0 - st.x) * st.y * g[tid] + bbv[tid];
    float o1 = (v1 - st.x) * st.y * g[tid + 256] + bbv[tid + 256];
    x[base + tid] = o0; x[base + tid + 256] = o1;
    xsp_write(xsp, blockIdx.x, tid, o0);
    xsp_write(xsp, blockIdx.x, tid + 256, o1);
}

// ---------------- combine 4 logit partials + bias -> out; softmax -> psp splits
__global__ __launch_bounds__(128) void softmax_out(
    const float* __restrict__ P, const float* __restrict__ e2v_b,
    float* __restrict__ out_i, f16* __restrict__ psp)
{
    __shared__ float red[4];
    int b = blockIdx.x, v = threadIdx.x, lane = v & 63, wv = v >> 6;
    bool valid = v < V1n;
    float s = -1e30f;
    if (valid) {
        s = e2v_b[v];
#pragma unroll
        for (int z = 0; z < 4; ++z) s += P[(size_t)z * Bb * 128 + (size_t)b * 128 + v];
        out_i[(size_t)b * V1n + v] = s;
    }
    float m = s;
#pragma unroll
    for (int off = 32; off; off >>= 1) m = fmaxf(m, __shfl_xor(m, off));
    if (!lane) red[wv] = m;
    __syncthreads();
    float M = fmaxf(red[0], red[1]);
    float e = valid ? expf(s - M) : 0.f;
    float d = e;
#pragma unroll
    for (int off = 32; off; off >>= 1) d += __shfl_xor(d, off);
    if (!lane) red[2 + wv] = d;
    __syncthreads();
    float D = red[2] + red[3];
    float p = valid ? e / D : 0.f;     // zero for pad cols 101..127
    f16 t2[2]; split2(p, t2);
    size_t o = (size_t)(v >> 3) * 8192 + (size_t)b * 8 + (v & 7);
    psp[o] = t2[0]; psp[PSP + o] = t2[1];
}

extern "C" void kernel_launch(void* const* d_in, const int* in_sizes, int n_in,
                              void* d_out, int out_size, void* d_ws, size_t ws_size,
                              hipStream_t stream)
{
    const int*   meanings = (const int*)  d_in[0];
    const float* emb      = (const float*)d_in[1];
    const float* v2e_w    = (const float*)d_in[2];
    const float* v2e_b    = (const float*)d_in[3];
    const float* e2v_w    = (const float*)d_in[4];
    const float* e2v_b    = (const float*)d_in[5];
    const float* sa_in_w  = (const float*)d_in[6];
    const float* sa_in_b  = (const float*)d_in[7];
    const float* sa_out_w = (const float*)d_in[8];
    const float* sa_out_b = (const float*)d_in[9];
    const float* ca_in_w  = (const float*)d_in[10];
    const float* ca_in_b  = (const float*)d_in[11];
    const float* ca_out_w = (const float*)d_in[12];
    const float* ca_out_b = (const float*)d_in[13];
    const float* ff1_w    = (const float*)d_in[14];
    const float* ff1_b    = (const float*)d_in[15];
    const float* ff2_w    = (const float*)d_in[16];
    const float* ff2_b    = (const float*)d_in[17];
    const float* ln_g     = (const float*)d_in[18];
    const float* ln_b     = (const float*)d_in[19];
    float* out = (float*)d_out;

    // ---- ws carve-out (~230 MB)
    char* wsb = (char*)d_ws;
    auto alloc = [&](size_t bytes) {
        char* p = wsb; wsb += (bytes + 255) & ~(size_t)255; return p;
    };
    const int nsain = 1536 * 512, nsaout = 512 * 512, nff1 = 2048 * 512,
              nff2 = 512 * 2048, nca = 512 * 512;
    f16 *wsp_sa_in[2], *wsp_sa_out[2], *wsp_ff1[2], *wsp_ff2[2];
    for (int l = 0; l < 2; ++l) wsp_sa_in[l]  = (f16*)alloc((size_t)2 * nsain * 2);
    for (int l = 0; l < 2; ++l) wsp_sa_out[l] = (f16*)alloc((size_t)2 * nsaout * 2);
    for (int l = 0; l < 2; ++l) wsp_ff1[l]    = (f16*)alloc((size_t)2 * nff1 * 2);
    for (int l = 0; l < 2; ++l) wsp_ff2[l]    = (f16*)alloc((size_t)2 * nff2 * 2);
    float* x       = (float*)alloc(BH * 4);
    f16*   xsp     = (f16*)  alloc(2 * BH * 2);                // frag-major; also attn-out
    float* cross   = (float*)alloc(2 * BH * 4);
    float* Pbuf    = (float*)alloc(8 * BH * 4);                // split-K partials (16.8MB)
    f16*   h1sp    = (f16*)  alloc(2 * (size_t)Bb * DFFn * 2); // frag-major
    f16*   psp     = (f16*)  alloc(2 * PSP * 2);               // probs splits (K pad 128)
    f16*   e2v_wsp = (f16*)  alloc((size_t)2 * 128 * 512 * 2); // N pad 101->128
    f16*   v2e_wsp = (f16*)  alloc((size_t)2 * 512 * 128 * 2); // K pad 101->128
    float* kc      = (float*)alloc((size_t)Ln * Tt * BH * 4);
    float* vc      = (float*)alloc((size_t)Ln * Tt * BH * 4);
    // setup-only aliases
    f16* ssp    = h1sp;
    f16* wspc_v = (f16*)Pbuf;
    f16* wspc_o = wspc_v + (size_t)2 * nca;
    f16* vssp   = wspc_o + (size_t)2 * nca;

    // ---- 1) split persistent weights into fragment-major fp16 planes
    const float* srcs[8] = { sa_in_w, sa_in_w + nsain, sa_out_w, sa_out_w + nsaout,
                             ff1_w, ff1_w + nff1, ff2_w, ff2_w + nff2 };
    f16* dsts[8] = { wsp_sa_in[0], wsp_sa_in[1], wsp_sa_out[0], wsp_sa_out[1],
                     wsp_ff1[0], wsp_ff1[1], wsp_ff2[0], wsp_ff2[1] };
    int nN[8] = { 1536, 1536, 512, 512, 2048, 2048, 512, 512 };
    int kb[8] = { 9, 9, 9, 9, 9, 9, 11, 11 };
    for (int i = 0; i < 8; ++i)
        split_mat<<<(nN[i] << kb[i]) / 256, 256, 0, stream>>>(
            srcs[i], dsts[i], nN[i], nN[i], 1 << kb[i], kb[i]);
    // vocab projections (padded)
    split_mat<<<(128 << 9) / 256, 256, 0, stream>>>(e2v_w, e2v_wsp, V1n, 128, 512, 9);
    split_mat<<<(512 << 7) / 256, 256, 0, stream>>>(v2e_w, v2e_wsp, 512, 512, V1n, 7);

    // ---- 2) setup: src embedding + per-layer cross-attn constant (S=1 shortcut)
    src_kernel<<<BH / 256, 256, 0, stream>>>(meanings, emb, ssp);
    for (int l = 0; l < Ln; ++l) {
        split_mat<<<nca / 256, 256, 0, stream>>>(
            ca_in_w + (size_t)l * 3 * Hdim * Hdim + (size_t)2 * Hdim * Hdim,
            wspc_v, 512, 512, 512, 9);
        split_mat<<<nca / 256, 256, 0, stream>>>(
            ca_out_w + (size_t)l * Hdim * Hdim, wspc_o, 512, 512, 512, 9);
        gemm_sp<3><<<dim3(4, 8, 1), 256, 0, stream>>>(
            ssp, wspc_v, ca_in_b + l * 1536 + 1024,
            nullptr, vssp, BH, 512, 512, 512, 0);
        gemm_sp<4><<<dim3(4, 8, 1), 256, 0, stream>>>(
            vssp, wspc_o, ca_out_b + l * 512,
            cross + (size_t)l * BH, nullptr, 0, 512, 512, 512, 0);
    }
    init_x<<<BH / 256, 256, 0, stream>>>(v2e_w, v2e_b, x, xsp);

    // ---- 3) autoregressive loop (incremental decode, KV cache)
    for (int i = 0; i < Tt; ++i) {
        for (int l = 0; l < Ln; ++l) {
            float* kcl = kc + (size_t)l * Tt * BH;
            float* vcl = vc + (size_t)l * Tt * BH;
            // QKV: N=1536, splitK2 -> 192 blocks; combined in attn_fused
            gemm_sp<0><<<dim3(12, 8, 2), 256, 0, stream>>>(
                xsp, wsp_sa_in[l], nullptr,
                Pbuf, nullptr, 0, 1536, 512, 256, 0);
            attn_fused<<<Bb, 256, 0, stream>>>(Pbuf, sa_in_b + l * 1536,
                                               kcl, vcl, xsp, i);
            // out-proj: N=512, splitK8 -> 256 blocks
            gemm_sp<0><<<dim3(4, 8, 8), 256, 0, stream>>>(
                xsp, wsp_sa_out[l], nullptr,
                Pbuf, nullptr, 0, 512, 512, 64, 0);
            ln12<8><<<Bb, 256, 0, stream>>>(x, Pbuf, sa_out_b + l * 512,
                cross + (size_t)l * BH,
                ln_g + (size_t)(l * 3 + 0) * Hdim, ln_b + (size_t)(l * 3 + 0) * Hdim,
                ln_g + (size_t)(l * 3 + 1) * Hdim, ln_b + (size_t)(l * 3 + 1) * Hdim,
                xsp);
            // FF1: N=2048, no split-K, epilogue relu+bias+split2 -> h1sp (128 blocks)
            gemm_sp<1><<<dim3(16, 8, 1), 256, 0, stream>>>(
                xsp, wsp_ff1[l], ff1_b + l * 2048,
                nullptr, h1sp, (size_t)Bb * DFFn, 2048, 512, 512, 0);
            // FF2: N=512, K=2048, splitK8 -> 256 blocks
            gemm_sp<0><<<dim3(4, 8, 8), 256, 0, stream>>>(
                h1sp, wsp_ff2[l], nullptr,
                Pbuf, nullptr, 0, 512, 2048, 256, 0);
            ln3<8><<<Bb, 256, 0, stream>>>(x, Pbuf, ff2_b + l * 512,
                ln_g + (size_t)(l * 3 + 2) * Hdim, ln_b + (size_t)(l * 3 + 2) * Hdim,
                xsp);
        }
        // logits: N=128 (pad of 101), splitK4 -> 32 blocks, partials in Pbuf
        gemm_sp<0><<<dim3(1, 8, 4), 256, 0, stream>>>(
            xsp, e2v_wsp, nullptr, Pbuf, nullptr, 0, 128, 512, 128, 0);
        // combine + write out[i] + softmax -> psp splits
        softmax_out<<<Bb, 128, 0, stream>>>(
            Pbuf, e2v_b, out + (size_t)i * Bb * V1n, psp);
        // x-update: x = probs @ v2e^T + b + pe(i+1)  (K=128 pad of 101)
        if (i + 1 < Tt)
            gemm_sp<5><<<dim3(4, 8, 1), 256, 0, stream>>>(
                psp, v2e_wsp, v2e_b, x, xsp, BH, 512, 128, 128, i + 1);
    }
}